// Round 1
// 268.845 us; speedup vs baseline: 1.1714x; 1.1714x over previous
//
#include <hip/hip_runtime.h>
#include <stdint.h>

#define NPIX 65536      // 256*256
#define NRE  65280      // right edges: 256 rows * 255
#define NE   130560     // total edges
#define NIMG 4
#define LTPB 1024                // local kernel threads (R8 showed fewer threads regress)
#define ETPB 1024                // endgame threads
#define NBLK_L (NIMG*32)         // 128 local blocks (32 tiles/image, 32x64 each)
#define TPIX 2048
#define EPAD 4096                // local edge-id space (H:[0,2048) V:[2048,4096))
#define KMAX 4096                // max components/image for LDS endgame (R5: K<=4096 held)
#define HSZ  1024                // endgame LDS dedupe hash slots (per buffer)
#define LHSZ 2048                // local emit dedupe hash slots
#define ECAP 4096                // endgame LDS edge-list capacity per buffer (n<=ECAP -> LDS)
typedef unsigned long long u64;

// union-find, path compression; roots stable within a phase -> races benign
__device__ __forceinline__ int ufind(unsigned* lbl, int x){
  int r = x, c = (int)lbl[r];
  while (c != r){ r = c; c = (int)lbl[r]; }
  while ((int)lbl[x] != r){ int n = (int)lbl[x]; lbl[x] = (unsigned)r; x = n; }
  return r;
}
__device__ __forceinline__ int ufind16(unsigned short* uf, int x){
  int r = x, c = (int)uf[r];
  while (c != r){ r = c; c = (int)uf[r]; }
  while ((int)uf[x] != r){ int n = (int)uf[x]; uf[x] = (unsigned short)r; x = n; }
  return r;
}

// merge two descending-sorted 5-lists (b into a)
__device__ __forceinline__ void merge5(float* a, const float* b){
  float out[5]; int ia = 0, ib = 0;
  #pragma unroll
  for (int k = 0; k < 5; ++k){
    float av = (ia < 5) ? a[ia] : -2.0f;
    float bv = (ib < 5) ? b[ib] : -2.0f;
    if (av >= bv){ out[k] = av; ++ia; } else { out[k] = bv; ++ib; }
  }
  #pragma unroll
  for (int k = 0; k < 5; ++k) a[k] = out[k];
}

// insert v into descending top-5
__device__ __forceinline__ void ins5(float* t5, float v){
  if (v > t5[4]){
    int j = 4;
    while (j > 0 && t5[j-1] < v){ t5[j] = t5[j-1]; --j; }
    t5[j] = v;
  }
}

// ---------------- local (tile) kernel: LDS union-find contraction ----------------
__global__ __launch_bounds__(LTPB)
void ph0_local(const float* __restrict__ prob, const float* __restrict__ roi,
               float* __restrict__ Fg, float* __restrict__ LIFEg,
               unsigned* __restrict__ LBLg, u64* __restrict__ LAg,
               unsigned* __restrict__ C, unsigned* __restrict__ C2,
               unsigned* __restrict__ MAPg, unsigned* __restrict__ KGg,
               float* __restrict__ T5g)
{
  const int blk = blockIdx.x;
  const int img = blk >> 5;
  const int tile = blk & 31;
  const int tr = tile >> 2, tc = tile & 3;     // 8 rows x 4 cols of tiles
  const int gr0 = tr*32, gc0 = tc*64;
  const int tid = threadIdx.x;
  const int lane = tid & 63;

  const float* pm = prob + img*NPIX;
  const float* rm = roi  + img*NPIX;
  float* F = Fg + img*NPIX;
  float* LIFE = LIFEg + img*NPIX;
  unsigned* LBL = LBLg + img*NPIX;
  unsigned* MAP = MAPg + img*NPIX;
  unsigned* KG  = KGg  + img*NPIX;
  u64* LA = LAg + (size_t)img*NE;

  __shared__ float          sf[TPIX];      // 8 KB
  __shared__ unsigned       slbl[TPIX];    // 8 KB (later: dedupe hash weights)
  __shared__ unsigned       smeb[2][TPIX]; // 16 KB double-buffered min-weight per root
                                           // (buffer 0 doubles as pos-map after the loop)
  __shared__ unsigned short el[2][EPAD];   // 16 KB ping-pong edge lists (free half: hash keys)
  __shared__ unsigned       aux[EPAD];     // 16 KB round-start roots (a|b<<16)
  __shared__ unsigned       bkw[192];      // cut-edge blocker weights
  __shared__ unsigned short bkp[192];      // blocker pixel (local id)
  __shared__ unsigned       s_fired[TPIX/32]; // 256 B: per-pixel died-bit (t5 dedupe)
  __shared__ float          s_t5w[(LTPB/64)*5]; // 320 B wave top-5s
  __shared__ int s_n[3];                   // rotating round counters

  float t5[5] = {-1.f,-1.f,-1.f,-1.f,-1.f};

  for (int p = tid; p < TPIX; p += LTPB){
    int gp = ((gr0 + (p>>6))<<8) + gc0 + (p&63);
    float fv = 1.0f - pm[gp]*rm[gp];
    sf[p] = fv; slbl[p] = (unsigned)p;
    smeb[0][p] = 0xFFFFFFFFu; smeb[1][p] = 0xFFFFFFFFu;
    F[gp] = fv; LIFE[gp] = 0.0f;
  }
  if (tid < 3) s_n[tid] = 0;
  if (tid < TPIX/32) s_fired[tid] = 0;
  // blocker table: for each tile-boundary pixel, min cut-edge weight
  for (int s = tid; s < 192; s += LTPB){
    unsigned wv = 0xFFFFFFFFu; int p = 0; int gq = -1;
    if (s < 32){ if (tc > 0){ p = s*64;        gq = ((gr0+s)<<8)    + gc0 - 1;  } }
    else if (s < 64){ int k=s-32;  if (tc < 3){ p = k*64+63;  gq = ((gr0+k)<<8)  + gc0 + 64; } }
    else if (s < 128){ int k=s-64; if (tr > 0){ p = k;        gq = ((gr0-1)<<8)  + gc0 + k;  } }
    else { int k=s-128;            if (tr < 7){ p = 31*64+k;  gq = ((gr0+32)<<8) + gc0 + k;  } }
    if (gq >= 0){
      int gp = ((gr0 + (p>>6))<<8) + gc0 + (p&63);
      float fp = 1.0f - pm[gp]*rm[gp];
      float fq = 1.0f - pm[gq]*rm[gq];
      wv = __float_as_uint(fmaxf(fp, fq));
    }
    bkw[s] = wv; bkp[s] = (unsigned short)p;
  }
  __syncthreads();                         // serves as barrier A of round 0

  // ---- local rounds: 2 barriers/round (sme double-buffered; resets overlap phase 2) ----
  int M = EPAD, cur = 0;
  for (int rd = 0; rd < 100000; ++rd){
    int nxt = cur ^ 1;
    unsigned* sme = smeb[rd & 1];          // reset during previous round's phase 2
    if (tid < 192){
      unsigned wv = bkw[tid];
      if (wv != 0xFFFFFFFFu) atomicMin(&sme[ufind(slbl, (int)bkp[tid])], wv);
    }
    int Mpad = (M + 63) & ~63;
    // phase 1: relabel, compact survivors, per-root min weight
    for (int idx = tid; idx < Mpad; idx += LTPB){
      bool keep = false; int e=0,u=0,v=0,a=0,b=0;
      if (idx < M){
        e = (rd == 0) ? idx : (int)el[cur][idx];
        bool valid;
        if (e < 2048){ u=e; v=e+1; valid = ((e&63)!=63); }
        else { u=e-2048; v=u+64; valid = ((u>>6)!=31); }
        if (valid){
          a = ufind(slbl,u); b = ufind(slbl,v);
          if (a != b){
            unsigned wb = __float_as_uint(fmaxf(sf[u],sf[v]));
            atomicMin(&sme[a],wb); atomicMin(&sme[b],wb);
            keep = true;
          }
        }
      }
      u64 m = __ballot(keep);
      if (m){
        int pos0 = __popcll(m & ((1ULL<<lane)-1));
        int leader = __ffsll((long long)m)-1;
        int base = 0;
        if (lane == leader) base = atomicAdd(&s_n[rd%3], __popcll(m));
        base = __shfl(base, leader);
        if (keep){
          el[nxt][base+pos0] = (unsigned short)e;
          aux[base+pos0] = (unsigned)a | ((unsigned)b<<16);
        }
      }
    }
    __syncthreads();                       // B: mins + list complete
    int n = s_n[rd%3];
    cur = nxt;
    // n == M  <=>  previous round had zero fires  =>  stable (blocked) state
    if (n == M || n == 0){ M = n; break; }
    M = n;
    // phase 2: fire via round-start roots (frozen in aux) — exact elder rule.
    // Also: reset next round's sme buffer + s_n slot (slot (rd+1)%3 last read
    // at round rd-2 after B — two barriers back -> safe).
    for (int idx = tid; idx < M; idx += LTPB){
      int e = (int)el[cur][idx];
      unsigned ab = aux[idx];
      int a = (int)(ab & 0xFFFFu), b = (int)(ab >> 16);
      int u, v;
      if (e < 2048){ u = e; v = e + 1; } else { u = e - 2048; v = u + 64; }
      float w = fmaxf(sf[u], sf[v]);
      unsigned wb = __float_as_uint(w);
      float fa = sf[a], fb = sf[b];
      bool bd = (fb < fa) || ((fb == fa) && (b < a));   // local order == global order in-tile
      int die = bd ? a : b, keep = bd ? b : a;
      if (sme[die] == wb){
        slbl[die] = (unsigned)keep;
        int gd = ((gr0 + (die>>6))<<8) + gc0 + (die&63);
        float lt = w - (bd ? fa : fb);
        LIFE[gd] = lt;                     // idempotent on equal-weight double-fire
        unsigned bbit = 1u << (die & 31);  // t5 insert is NOT idempotent -> dedupe
        if (!(atomicOr(&s_fired[die >> 5], bbit) & bbit)) ins5(t5, lt);
      }
    }
    {
      unsigned* smeN = smeb[(rd+1) & 1];
      for (int i = tid; i < TPIX; i += LTPB) smeN[i] = 0xFFFFFFFFu;
      if (tid == 0) s_n[(rd+1)%3] = 0;
    }
    __syncthreads();                       // A of round rd+1
  }

  // ---- final relabel, compact roots to dense per-image ids ----
  unsigned* posm = smeb[0];                // pos map (only root entries written/read)
  for (int p = tid; p < TPIX; p += LTPB){
    int r = ufind(slbl, p);
    int gp = ((gr0 + (p>>6))<<8) + gc0 + (p&63);
    LBL[gp] = (unsigned)(((gr0 + (r>>6))<<8) + gc0 + (r&63));
  }
  __syncthreads();                         // slbl fully compressed
  for (int p = tid; p < TPIX; p += LTPB){
    if ((int)slbl[p] == p){
      unsigned pos = atomicAdd(&C2[img], 1u);
      posm[p] = pos;                       // in-tile pos map
      unsigned gp = (unsigned)(((gr0 + (p>>6))<<8) + gc0 + (p&63));
      MAP[gp] = pos;
      KG[pos] = gp;
    }
  }
  __syncthreads();

  // ---- emit surviving internal edges, deduped per root-pair ----
  unsigned* hk = (unsigned*)&el[cur ^ 1][0];   // 2048 u32 slots (free ping-pong half)
  unsigned* hw = slbl;                          // 2048 u32 slots (dead)
  for (int i = tid; i < LHSZ; i += LTPB){ hk[i] = 0xFFFFFFFFu; hw[i] = 0xFFFFFFFFu; }
  __syncthreads();

  unsigned* ctr = &C[img];
  int Mpad2 = (M + 63) & ~63;
  for (int idx = tid; idx < Mpad2; idx += LTPB){
    bool spill = false;
    u64 rec = 0;
    if (idx < M){
      int e = (int)el[cur][idx];
      unsigned ab = aux[idx];              // round-start roots == final roots (0 fires)
      int a = (int)(ab & 0xFFFFu), b = (int)(ab >> 16);
      int u, v;
      if (e < 2048){ u = e; v = e + 1; } else { u = e - 2048; v = u + 64; }
      unsigned wb = __float_as_uint(fmaxf(sf[u], sf[v]));
      int lo = a < b ? a : b, hi = a < b ? b : a;
      unsigned key = ((unsigned)lo << 11) | (unsigned)hi;   // a,b < 2048 -> 22 bits
      unsigned h = ((key * 2654435761u) >> 21) & (LHSZ-1);
      bool ins = false;
      #pragma unroll
      for (int t = 0; t < 8; ++t){
        unsigned old = atomicCAS(&hk[h], 0xFFFFFFFFu, key);
        if (old == 0xFFFFFFFFu || old == key){ atomicMin(&hw[h], wb); ins = true; break; }
        h = (h + 1) & (LHSZ-1);
      }
      if (!ins){
        spill = true;
        rec = ((u64)wb << 32) | ((u64)posm[a] << 16) | posm[b];
      }
    }
    u64 m = __ballot(spill);
    if (m){
      int pos0 = __popcll(m & ((1ULL<<lane)-1));
      int leader = __ffsll((long long)m)-1;
      unsigned base = 0;
      if (lane == leader) base = atomicAdd(ctr, (unsigned)__popcll(m));
      base = (unsigned)__shfl((int)base, leader);
      if (spill) LA[base + pos0] = rec;
    }
  }
  __syncthreads();
  // flush hash: one record per distinct pair, weight = pair min
  for (int h = tid; h < LHSZ; h += LTPB){
    unsigned key = hk[h];
    bool ok = (key != 0xFFFFFFFFu);
    u64 rec = 0;
    if (ok){
      int a = (int)(key >> 11), b = (int)(key & 0x7FFu);
      rec = ((u64)hw[h] << 32) | ((u64)posm[a] << 16) | posm[b];
    }
    u64 m = __ballot(ok);
    if (m){
      int pos0 = __popcll(m & ((1ULL<<lane)-1));
      int leader = __ffsll((long long)m)-1;
      unsigned base = 0;
      if (lane == leader) base = atomicAdd(ctr, (unsigned)__popcll(m));
      base = (unsigned)__shfl((int)base, leader);
      if (ok) LA[base + pos0] = rec;
    }
  }

  // ---- block top-5 of locally-died bars -> T5g[blk*5..+5) ----
  #pragma unroll
  for (int off = 1; off < 64; off <<= 1){
    float o[5];
    #pragma unroll
    for (int k = 0; k < 5; ++k) o[k] = __shfl_xor(t5[k], off);
    merge5(t5, o);
  }
  if (lane == 0){
    int wv = tid >> 6;
    #pragma unroll
    for (int k = 0; k < 5; ++k) s_t5w[wv*5+k] = t5[k];
  }
  __syncthreads();
  if (tid < 64){
    float u5[5];
    #pragma unroll
    for (int k = 0; k < 5; ++k) u5[k] = (tid < LTPB/64) ? s_t5w[tid*5+k] : -2.0f;
    #pragma unroll
    for (int off = 1; off < 16; off <<= 1){
      float o[5];
      #pragma unroll
      for (int k = 0; k < 5; ++k) o[k] = __shfl_xor(u5[k], off);
      merge5(u5, o);
    }
    if (tid == 0){
      #pragma unroll
      for (int k = 0; k < 5; ++k) T5g[blk*5+k] = u5[k];
    }
  }
}

// fallback rounds (K>KMAX, safety net) — global arrays, fmt16, no dedupe
#define RUN_ROUNDS_GLOBAL(UF, ME, RNK)                                       \
  for (int k = tid; k < K; k += ETPB){                                       \
    unsigned g = kg[k];                                                      \
    UF[k] = (unsigned short)k;                                               \
    RNK[k] = ((u64)__float_as_uint(f[g]) << 32) | g;                         \
  }                                                                          \
  __syncthreads();                                                           \
  for (int rd = 0; rd < 70000 && n > 0; ++rd){                               \
    for (int k = tid; k < K; k += ETPB) ME[k] = 0xFFFFFFFFu;                 \
    if (tid == 0) s_n[0] = 0;                                                \
    __syncthreads();                                                         \
    int Mpad = (n + 63) & ~63;                                               \
    for (int idx = tid; idx < Mpad; idx += ETPB){                            \
      bool keep = false; unsigned wb = 0; int a = 0, b = 0;                  \
      if (idx < n){                                                          \
        u64 rec = src[idx];                                                  \
        wb = (unsigned)(rec >> 32);                                          \
        a = (int)((rec >> 16) & 0xFFFFu);                                    \
        b = (int)(rec & 0xFFFFu);                                            \
        a = ufind16(UF, a); b = ufind16(UF, b);                              \
        if (a != b){ atomicMin(&ME[a], wb); atomicMin(&ME[b], wb); keep = true; } \
      }                                                                      \
      u64 m = __ballot(keep);                                                \
      if (m){                                                                \
        int pos0 = __popcll(m & ((1ULL<<lane)-1));                           \
        int leader = __ffsll((long long)m)-1;                                \
        int base = 0;                                                        \
        if (lane == leader) base = atomicAdd(&s_n[0], __popcll(m));          \
        base = __shfl(base, leader);                                         \
        if (keep) dst[base+pos0] = ((u64)wb<<32)|((u64)(unsigned)a<<16)|(unsigned)b; \
      }                                                                      \
    }                                                                        \
    __syncthreads();                                                         \
    int nn = s_n[0];                                                         \
    for (int idx = tid; idx < nn; idx += ETPB){                              \
      u64 rec = dst[idx];                                                    \
      unsigned wb = (unsigned)(rec >> 32);                                   \
      int a = (int)((rec >> 16) & 0xFFFFu);                                  \
      int b = (int)(rec & 0xFFFFu);                                          \
      bool bd = RNK[b] < RNK[a];                                             \
      int die = bd ? a : b, kp = bd ? b : a;                                 \
      if (ME[die] == wb){                                                    \
        UF[die] = (unsigned short)kp;                                        \
        u64 rk = RNK[die];                                                   \
        life[(unsigned)(rk & 0xFFFFFFFFu)] =                                 \
            __uint_as_float(wb) - __uint_as_float((unsigned)(rk >> 32));     \
      }                                                                      \
    }                                                                        \
    __syncthreads();                                                         \
    u64* t = src; src = dst; dst = t; n = nn;                                \
  }

// ---------------- endgame: 1 block/image, all-LDS UF + ranks + edge lists ----------------
__global__ __launch_bounds__(ETPB)
void ph0_endgame(const float* __restrict__ Fg, float* __restrict__ LIFEg,
                 unsigned* __restrict__ LBLg, unsigned* __restrict__ MAPg,
                 unsigned* __restrict__ KGg, u64* __restrict__ LAg,
                 u64* __restrict__ LBg, u64* __restrict__ GRg,
                 const unsigned* __restrict__ C, const unsigned* __restrict__ C2,
                 const float* __restrict__ T5g,
                 float* __restrict__ LOSS, unsigned* __restrict__ DONE,
                 float* __restrict__ out)
{
  const int img = blockIdx.x, tid = threadIdx.x;
  const int lane = tid & 63;
  const float* f = Fg + img*NPIX;
  float* life = LIFEg + img*NPIX;
  unsigned* lblg = LBLg + img*NPIX;
  unsigned* map  = MAPg + img*NPIX;
  const unsigned* kg = KGg + img*NPIX;
  u64* src = LAg + (size_t)img*NE;
  u64* dst = LBg + (size_t)img*NE;
  u64* rnk = GRg + (size_t)img*NPIX;   // fallback-path ranks only

  // 156.5 KB LDS (gfx950 allows up to 160 KB/workgroup; 4 blocks -> occupancy moot)
  __shared__ unsigned short s_uf[KMAX];          //  8 KB
  __shared__ unsigned s_meB[2*KMAX];             // 32 KB (double-buffered min/root)
  __shared__ unsigned s_hkB[2*HSZ];              //  8 KB (2 x 1024 hash keys)
  __shared__ unsigned s_hwB[2*HSZ];              //  8 KB (2 x 1024 hash weights)
  __shared__ u64 s_rnk[KMAX];                    // 32 KB ranks (was global -> cross-XCD L3)
  __shared__ u64 s_lstA[ECAP];                   // 32 KB LDS edge list ping
  __shared__ u64 s_lstB[ECAP];                   // 32 KB LDS edge list pong
  __shared__ unsigned s_fired[KMAX/32];          // 512 B died-bit (t5 dedupe)
  __shared__ float s_w5[(ETPB/64)*5];            // 320 B
  __shared__ int s_n[3];

  const int K = (int)C2[img];
  const int nInt = (int)C[img];

  // append the 2560 cut edges (translated to compact ids, fmt16)
  for (int s = tid; s < 2560; s += ETPB){
    int gu, gv;
    if (s < 768){ int ci = s >> 8, row = s & 255, col = 63 + (ci<<6); gu = (row<<8)+col; gv = gu+1; }
    else { int k = s - 768; int ri = k >> 8, colh = k & 255, gr = 31 + (ri<<5); gu = (gr<<8)+colh; gv = gu+256; }
    unsigned ia = map[lblg[gu]];
    unsigned ib = map[lblg[gv]];
    unsigned wb = __float_as_uint(fmaxf(f[gu], f[gv]));
    src[nInt + s] = ((u64)wb << 32) | ((u64)ia << 16) | ib;
  }
  if (tid < 3) s_n[tid] = 0;
  int n = nInt + 2560;

  float t5[5] = {-1.f,-1.f,-1.f,-1.f,-1.f};

  if (K <= KMAX){
    // init: uf, LDS rank, me[0], hash[0], fired bits, local-phase top-5s
    for (int k = tid; k < K; k += ETPB){
      unsigned g = kg[k];
      s_uf[k] = (unsigned short)k;
      s_rnk[k] = ((u64)__float_as_uint(f[g]) << 32) | g;   // (birth fbits, pixel): lower = deeper
      s_meB[k] = 0xFFFFFFFFu;
    }
    for (int h = tid; h < HSZ; h += ETPB){ s_hkB[h] = 0xFFFFFFFFu; s_hwB[h] = 0xFFFFFFFFu; }
    if (tid < KMAX/32) s_fired[tid] = 0;
    if (tid < 32*5) ins5(t5, T5g[img*(32*5) + tid]);   // merge local tiles' top-5s
    __syncthreads();

    u64 *lsrc = s_lstA, *ldst = s_lstB;
    bool sL = false;                       // src list currently in LDS?

    for (int rd = 0; rd < 70000; ++rd){
      const int bi = rd & 1;
      unsigned* me = s_meB + bi*KMAX;
      unsigned* hk = s_hkB + bi*HSZ;
      unsigned* hw = s_hwB + bi*HSZ;
      const bool useHash = (n > 1024);
      const bool dL = (n <= ECAP);         // appends <= n, so dst fits in LDS
      int Mpad = (n + 63) & ~63;
      // pass A: relabel; hash-dedupe (big rounds) or direct mins; append live
      for (int idx = tid; idx < Mpad; idx += ETPB){
        bool app = false; unsigned wb = 0; int a = 0, b = 0;
        if (idx < n){
          u64 rec = sL ? lsrc[idx] : src[idx];
          a = (int)((rec >> 16) & 0xFFFFu);
          b = (int)(rec & 0xFFFFu);
          a = ufind16(s_uf, a); b = ufind16(s_uf, b);
          if (a != b){
            wb = (unsigned)(rec >> 32);
            if (useHash){
              int lo = a < b ? a : b, hi = a < b ? b : a;
              unsigned key = ((unsigned)lo << 12) | (unsigned)hi;   // ids<4096 -> 24 bits
              unsigned h = ((key * 2654435761u) >> 20) & (HSZ-1);
              bool ins = false;
              #pragma unroll
              for (int t = 0; t < 8; ++t){
                unsigned old = atomicCAS(&hk[h], 0xFFFFFFFFu, key);
                if (old == 0xFFFFFFFFu || old == key){ atomicMin(&hw[h], wb); ins = true; break; }
                h = (h + 1) & (HSZ-1);
              }
              if (!ins){ atomicMin(&me[a], wb); atomicMin(&me[b], wb); app = true; }
            } else {
              atomicMin(&me[a], wb); atomicMin(&me[b], wb); app = true;
            }
          }
        }
        u64 m = __ballot(app);
        if (m){
          int pos0 = __popcll(m & ((1ULL<<lane)-1));
          int leader = __ffsll((long long)m)-1;
          int base = 0;
          if (lane == leader) base = atomicAdd(&s_n[rd%3], __popcll(m));
          base = __shfl(base, leader);
          if (app){
            u64 r = ((u64)wb<<32)|((u64)(unsigned)a<<16)|(unsigned)b;
            if (dL) ldst[base+pos0] = r; else dst[base+pos0] = r;
          }
        }
      }
      __syncthreads();                      // B1
      if (useHash){
        // pass B: flush hash — one deduped record per pair
        for (int h = tid; h < HSZ; h += ETPB){
          unsigned key = hk[h];
          bool okk = (key != 0xFFFFFFFFu);
          unsigned wb = 0; int a = 0, b = 0;
          if (okk){
            a = (int)(key >> 12); b = (int)(key & 0xFFFu);
            wb = hw[h];
            atomicMin(&me[a], wb); atomicMin(&me[b], wb);
          }
          u64 m = __ballot(okk);
          if (m){
            int pos0 = __popcll(m & ((1ULL<<lane)-1));
            int leader = __ffsll((long long)m)-1;
            int base = 0;
            if (lane == leader) base = atomicAdd(&s_n[rd%3], __popcll(m));
            base = __shfl(base, leader);
            if (okk){
              u64 r = ((u64)wb<<32)|((u64)(unsigned)a<<16)|(unsigned)b;
              if (dL) ldst[base+pos0] = r; else dst[base+pos0] = r;
            }
          }
        }
        __syncthreads();                    // B2 (only on hashed rounds)
      }
      int nn = s_n[rd%3];
      if (nn == 0) break;                   // endgame always progresses; exits via n==0
      // pass C: fire via pass-A roots (frozen in records) — exact elder rule.
      // Lifetimes go straight into the t5 registers (fired-bit dedupes
      // equal-weight double-fires). No life[] writes in this path.
      for (int idx = tid; idx < nn; idx += ETPB){
        u64 rec = dL ? ldst[idx] : dst[idx];
        unsigned wb = (unsigned)(rec >> 32);
        int a = (int)((rec >> 16) & 0xFFFFu);
        int b = (int)(rec & 0xFFFFu);
        u64 ra = s_rnk[a], rb = s_rnk[b];
        bool bd = rb < ra;
        int die = bd ? a : b, kp = bd ? b : a;
        if (me[die] == wb){
          s_uf[die] = (unsigned short)kp;
          unsigned bbit = 1u << (die & 31);
          if (!(atomicOr(&s_fired[die >> 5], bbit) & bbit)){
            u64 rk = bd ? ra : rb;
            ins5(t5, __uint_as_float(wb) - __uint_as_float((unsigned)(rk >> 32)));
          }
        }
      }
      {
        unsigned* meN = s_meB + (bi^1)*KMAX;
        for (int k = tid; k < K; k += ETPB) meN[k] = 0xFFFFFFFFu;
        if (nn > 1024){
          unsigned* hkN = s_hkB + (bi^1)*HSZ;
          unsigned* hwN = s_hwB + (bi^1)*HSZ;
          for (int h = tid; h < HSZ; h += ETPB){ hkN[h] = 0xFFFFFFFFu; hwN[h] = 0xFFFFFFFFu; }
        }
        if (tid == 0) s_n[(rd+1)%3] = 0;
      }
      __syncthreads();                      // C
      { u64* t = src; src = dst; dst = t; }
      { u64* t = lsrc; lsrc = ldst; ldst = t; }
      sL = dL;
      n = nn;
    }
  } else {
    __syncthreads();
    unsigned short* g_uf = (unsigned short*)lblg;   // dead after translation
    unsigned*       g_me = map;                     // dead after translation
    u64*            g_rnk = rnk;
    RUN_ROUNDS_GLOBAL(g_uf, g_me, g_rnk)
    // fallback path: lifetimes live in life[] (local fires + fallback fires)
    for (int i = tid; i < NPIX; i += ETPB) ins5(t5, life[i]);
  }

  // ---- top-5 via shuffle butterfly -> per-image loss ----
  #pragma unroll
  for (int off = 1; off < 64; off <<= 1){
    float o[5];
    #pragma unroll
    for (int k = 0; k < 5; ++k) o[k] = __shfl_xor(t5[k], off);
    merge5(t5, o);
  }
  if (lane == 0){
    int wv = tid >> 6;
    #pragma unroll
    for (int k = 0; k < 5; ++k) s_w5[wv*5+k] = t5[k];
  }
  __syncthreads();
  if (tid < 64){
    float u5[5];
    #pragma unroll
    for (int k = 0; k < 5; ++k) u5[k] = (tid < ETPB/64) ? s_w5[tid*5+k] : -2.0f;
    #pragma unroll
    for (int off = 1; off < 16; off <<= 1){
      float o[5];
      #pragma unroll
      for (int k = 0; k < 5; ++k) o[k] = __shfl_xor(u5[k], off);
      merge5(u5, o);
    }
    if (tid == 0){
      float lsum = 0.0f;
      #pragma unroll
      for (int k = 0; k < 5; ++k){ float d = u5[k] - 0.5f; lsum += d*d; }  // TARGET_LIFETIME
      atomicExch(&LOSS[img], lsum * 0.2f);   // n_use = 5 always (65535 valid pairs)
      __threadfence();
      unsigned prev = atomicAdd(DONE, 1u);
      if (prev == NIMG - 1){
        float s = 0.0f;
        #pragma unroll
        for (int i = 0; i < NIMG; ++i) s += atomicAdd(&LOSS[i], 0.0f);
        out[0] = s * 25.0f;                  // mean over 4 * LOSS_SCALE(100)
      }
    }
  }
}

extern "C" void kernel_launch(void* const* d_in, const int* in_sizes, int n_in,
                              void* d_out, int out_size, void* d_ws, size_t ws_size,
                              hipStream_t stream)
{
  const float* prob = (const float*)d_in[0];
  const float* roi  = (const float*)d_in[1];
  char* ws = (char*)d_ws;
  const size_t SZL = (size_t)4*NE*8;              // 4,177,920 B per list
  float*    F    = (float*)(ws);
  float*    LIFE = (float*)(ws + (1u<<20));
  unsigned* LBL  = (unsigned*)(ws + (2u<<20));
  unsigned* MAP  = (unsigned*)(ws + (3u<<20));
  unsigned* KG   = (unsigned*)(ws + (4u<<20));
  u64*      LA   = (u64*)(ws + (5u<<20));
  u64*      LB   = (u64*)(ws + (5u<<20) + SZL);
  u64*      GR   = (u64*)(ws + (5u<<20) + 2*SZL);
  unsigned* C    = (unsigned*)(ws + (5u<<20) + 2*SZL + (2u<<20));
  unsigned* C2   = C + 4;
  unsigned* DONE = C + 8;
  float*    LOSS = (float*)((char*)C + 64);
  // T5 (128 tiles x 5 floats = 2560 B) carved from LB's tail: endgame global-dst
  // writes use at most n0 << NE-320 entries of each image slice, so the last
  // 320 u64 of the LB region are provably never touched.
  float*    T5   = (float*)(ws + (5u<<20) + 2*SZL - 2560);
  float*    out  = (float*)d_out;

  hipMemsetAsync(C, 0, 64, stream);   // C, C2, DONE (capture-safe memset node)
  ph0_local<<<NBLK_L, LTPB, 0, stream>>>(prob, roi, F, LIFE, LBL, LA, C, C2, MAP, KG, T5);
  ph0_endgame<<<NIMG, ETPB, 0, stream>>>(F, LIFE, LBL, MAP, KG, LA, LB, GR, C, C2, T5, LOSS, DONE, out);
}

// Round 3
// 262.398 us; speedup vs baseline: 1.2002x; 1.0246x over previous
//
#include <hip/hip_runtime.h>
#include <stdint.h>

#define NPIX 65536      // 256*256
#define NRE  65280      // right edges: 256 rows * 255
#define NE   130560     // total edges
#define NIMG 4
#define LTPB 1024                // local kernel threads (R8 showed fewer threads regress)
#define ETPB 1024                // endgame threads
#define NBLK_L (NIMG*32)         // 128 local blocks (32 tiles/image, 32x64 each)
#define TPIX 2048
#define EPAD 4096                // local edge-id space (H:[0,2048) V:[2048,4096))
#define KMAX 4096                // max components/image for LDS endgame (R5: K<=4096 held)
#define HSZ  1024                // endgame LDS dedupe hash slots (per buffer)
#define LHSZ 2048                // local emit dedupe hash slots
#define ECAP 4096                // endgame LDS edge-list slots per buffer (hybrid: spill->global)
#define NCUT 2560                // cut edges per image (3*256 vertical + 7*256 horizontal)
typedef unsigned long long u64;

// union-find, path compression; ONLY safe while roots are stable (no concurrent fires)
__device__ __forceinline__ int ufind(unsigned* lbl, int x){
  int r = x, c = (int)lbl[r];
  while (c != r){ r = c; c = (int)lbl[r]; }
  while ((int)lbl[x] != r){ int n = (int)lbl[x]; lbl[x] = (unsigned)r; x = n; }
  return r;
}
__device__ __forceinline__ int ufind16(unsigned short* uf, int x){
  int r = x, c = (int)uf[r];
  while (c != r){ r = c; c = (int)uf[r]; }
  while ((int)uf[x] != r){ int n = (int)uf[x]; uf[x] = (unsigned short)r; x = n; }
  return r;
}
// fire-concurrent-safe flatten: read-only walk, never writes a root entry.
// (Fires only target current roots; x is written only if already a non-root,
// and every pointer write strictly decreases rank -> no cycles, terminates.)
__device__ __forceinline__ void uflat(unsigned* lbl, int x){
  int r = (int)lbl[x];
  if (r == x) return;                  // root: a concurrent fire may own it; don't touch
  int c = (int)lbl[r];
  while (c != r){ r = c; c = (int)lbl[r]; }
  lbl[x] = (unsigned)r;                // non-root: no fire can target it; single write
}
__device__ __forceinline__ void uflat16(unsigned short* uf, int x){
  int r = (int)uf[x];
  if (r == x) return;
  int c = (int)uf[r];
  while (c != r){ r = c; c = (int)uf[r]; }
  uf[x] = (unsigned short)r;
}

// merge two descending-sorted 5-lists (b into a)
__device__ __forceinline__ void merge5(float* a, const float* b){
  float out[5]; int ia = 0, ib = 0;
  #pragma unroll
  for (int k = 0; k < 5; ++k){
    float av = (ia < 5) ? a[ia] : -2.0f;
    float bv = (ib < 5) ? b[ib] : -2.0f;
    if (av >= bv){ out[k] = av; ++ia; } else { out[k] = bv; ++ib; }
  }
  #pragma unroll
  for (int k = 0; k < 5; ++k) a[k] = out[k];
}

// insert v into descending top-5
__device__ __forceinline__ void ins5(float* t5, float v){
  if (v > t5[4]){
    int j = 4;
    while (j > 0 && t5[j-1] < v){ t5[j] = t5[j-1]; --j; }
    t5[j] = v;
  }
}

// ---------------- local (tile) kernel: LDS union-find contraction ----------------
// Outputs per image: LIFE (per-pixel lifetimes of locally-died bars), CID (per-pixel
// compact component id), CUTW (cut-edge weights), RNKI (per-component rank record),
// LA (deduped surviving internal edges, compact ids), T5 (per-tile top-5 lifetimes).
__global__ __launch_bounds__(LTPB)
void ph0_local(const float* __restrict__ prob, const float* __restrict__ roi,
               float* __restrict__ LIFEg, unsigned* __restrict__ CIDg,
               u64* __restrict__ LAg,
               unsigned* __restrict__ C, unsigned* __restrict__ C2,
               unsigned* __restrict__ CUTWg, u64* __restrict__ RNKIg,
               float* __restrict__ T5g)
{
  const int blk = blockIdx.x;
  const int img = blk >> 5;
  const int tile = blk & 31;
  const int tr = tile >> 2, tc = tile & 3;     // 8 rows x 4 cols of tiles
  const int gr0 = tr*32, gc0 = tc*64;
  const int tid = threadIdx.x;
  const int lane = tid & 63;

  const float* pm = prob + img*NPIX;
  const float* rm = roi  + img*NPIX;
  float* LIFE = LIFEg + img*NPIX;
  unsigned* CID = CIDg + img*NPIX;
  unsigned* CUTW = CUTWg + img*NCUT;
  u64* RNKI = RNKIg + (size_t)img*NPIX;
  u64* LA = LAg + (size_t)img*NE;

  __shared__ float          sf[TPIX];      // 8 KB
  __shared__ unsigned       slbl[TPIX];    // 8 KB (later: dedupe hash weights)
  __shared__ unsigned       smeb[2][TPIX]; // 16 KB double-buffered min-weight per root
                                           // (buffer 0 doubles as pos-map after the loop)
  __shared__ float          slife[TPIX];   // 8 KB per-pixel lifetimes (flushed after loop)
  __shared__ unsigned short el[2][EPAD];   // 16 KB ping-pong edge lists (free half: hash keys)
  __shared__ unsigned       aux[EPAD];     // 16 KB round-start roots (a|b<<16)
  __shared__ unsigned       bkw[192];      // cut-edge blocker weights
  __shared__ unsigned short bkp[192];      // blocker pixel (local id)
  __shared__ unsigned       s_fired[TPIX/32]; // 256 B: per-pixel died-bit (t5 dedupe)
  __shared__ float          s_t5w[(LTPB/64)*5]; // 320 B wave top-5s
  __shared__ int s_n[3];                   // rotating round counters

  float t5[5] = {-1.f,-1.f,-1.f,-1.f,-1.f};

  for (int p = tid; p < TPIX; p += LTPB){
    int gp = ((gr0 + (p>>6))<<8) + gc0 + (p&63);
    float fv = 1.0f - pm[gp]*rm[gp];
    sf[p] = fv; slbl[p] = (unsigned)p;
    smeb[0][p] = 0xFFFFFFFFu; smeb[1][p] = 0xFFFFFFFFu;
    slife[p] = 0.0f;
  }
  if (tid < 3) s_n[tid] = 0;
  if (tid < TPIX/32) s_fired[tid] = 0;
  // blocker table: for each tile-boundary pixel, min cut-edge weight
  for (int s = tid; s < 192; s += LTPB){
    unsigned wv = 0xFFFFFFFFu; int p = 0; int gq = -1;
    if (s < 32){ if (tc > 0){ p = s*64;        gq = ((gr0+s)<<8)    + gc0 - 1;  } }
    else if (s < 64){ int k=s-32;  if (tc < 3){ p = k*64+63;  gq = ((gr0+k)<<8)  + gc0 + 64; } }
    else if (s < 128){ int k=s-64; if (tr > 0){ p = k;        gq = ((gr0-1)<<8)  + gc0 + k;  } }
    else { int k=s-128;            if (tr < 7){ p = 31*64+k;  gq = ((gr0+32)<<8) + gc0 + k;  } }
    if (gq >= 0){
      int gp = ((gr0 + (p>>6))<<8) + gc0 + (p&63);
      float fp = 1.0f - pm[gp]*rm[gp];
      float fq = 1.0f - pm[gq]*rm[gq];
      wv = __float_as_uint(fmaxf(fp, fq));
    }
    bkw[s] = wv; bkp[s] = (unsigned short)p;
  }
  __syncthreads();                         // serves as barrier A of round 0

  // export owned cut-edge weights (right cols if tc<3, bottom rows if tr<7).
  // Slot layout matches endgame enumeration: vertical (ci<<8)|row, horizontal 768+(ri<<8)+col.
  if (tid < 192){
    int s = tid;
    if (s >= 32 && s < 64  && tc < 3) CUTW[(tc<<8) | (gr0 + (s-32))] = bkw[s];
    if (s >= 128           && tr < 7) CUTW[768 + (tr<<8) + (gc0 + (s-128))] = bkw[s];
  }

  // ---- local rounds: 2 barriers/round; NO global memory ops inside the loop ----
  int M = EPAD, cur = 0;
  for (int rd = 0; rd < 100000; ++rd){
    int nxt = cur ^ 1;
    unsigned* sme = smeb[rd & 1];          // reset during previous round's phase 2
    int bs = tid - (LTPB - 192);           // blockers on HIGH threads (low ones start phase 1)
    if (bs >= 0){
      unsigned wv = bkw[bs];
      if (wv != 0xFFFFFFFFu) atomicMin(&sme[ufind(slbl, (int)bkp[bs])], wv);
    }
    int Mpad = (M + 63) & ~63;
    // phase 1: relabel, compact survivors, per-root min weight
    for (int idx = tid; idx < Mpad; idx += LTPB){
      bool keep = false; int e=0,u=0,v=0,a=0,b=0;
      if (idx < M){
        e = (rd == 0) ? idx : (int)el[cur][idx];
        bool valid;
        if (e < 2048){ u=e; v=e+1; valid = ((e&63)!=63); }
        else { u=e-2048; v=u+64; valid = ((u>>6)!=31); }
        if (valid){
          a = ufind(slbl,u); b = ufind(slbl,v);
          if (a != b){
            unsigned wb = __float_as_uint(fmaxf(sf[u],sf[v]));
            atomicMin(&sme[a],wb); atomicMin(&sme[b],wb);
            keep = true;
          }
        }
      }
      u64 m = __ballot(keep);
      if (m){
        int pos0 = __popcll(m & ((1ULL<<lane)-1));
        int leader = __ffsll((long long)m)-1;
        int base = 0;
        if (lane == leader) base = atomicAdd(&s_n[rd%3], __popcll(m));
        base = __shfl(base, leader);
        if (keep){
          el[nxt][base+pos0] = (unsigned short)e;
          aux[base+pos0] = (unsigned)a | ((unsigned)b<<16);
        }
      }
    }
    __syncthreads();                       // B: mins + list complete
    int n = s_n[rd%3];
    cur = nxt;
    // n == M  <=>  previous round had zero fires  =>  stable (blocked) state
    if (n == M || n == 0){ M = n; break; }
    M = n;
    // phase 2: fire via round-start roots (frozen in aux) — exact elder rule.
    for (int idx = tid; idx < M; idx += LTPB){
      int e = (int)el[cur][idx];
      unsigned ab = aux[idx];
      int a = (int)(ab & 0xFFFFu), b = (int)(ab >> 16);
      int u, v;
      if (e < 2048){ u = e; v = e + 1; } else { u = e - 2048; v = u + 64; }
      float w = fmaxf(sf[u], sf[v]);
      unsigned wb = __float_as_uint(w);
      float fa = sf[a], fb = sf[b];
      bool bd = (fb < fa) || ((fb == fa) && (b < a));   // local order == global order in-tile
      int die = bd ? a : b, keep = bd ? b : a;
      if (sme[die] == wb){
        slbl[die] = (unsigned)keep;
        float lt = w - (bd ? fa : fb);
        slife[die] = lt;                   // idempotent on equal-weight double-fire
        unsigned bbit = 1u << (die & 31);  // t5 insert is NOT idempotent -> dedupe
        if (!(atomicOr(&s_fired[die >> 5], bbit) & bbit)) ins5(t5, lt);
      }
    }
    // fire-safe flatten (uflat never writes a root -> cannot undo a concurrent fire)
    for (int p = tid; p < TPIX; p += LTPB) uflat(slbl, p);
    {
      unsigned* smeN = smeb[(rd+1) & 1];
      for (int i = tid; i < TPIX; i += LTPB) smeN[i] = 0xFFFFFFFFu;
      if (tid == 0) s_n[(rd+1)%3] = 0;
    }
    __syncthreads();                       // A of round rd+1
  }

  // ---- compact roots to dense per-image ids, export rank records ----
  unsigned* posm = smeb[0];                // pos map (only root entries written/read)
  for (int p = tid; p < TPIX; p += LTPB){
    if ((int)slbl[p] == p){
      unsigned pos = atomicAdd(&C2[img], 1u);
      posm[p] = pos;
      unsigned gp = (unsigned)(((gr0 + (p>>6))<<8) + gc0 + (p&63));
      RNKI[pos] = ((u64)__float_as_uint(sf[p]) << 32) | gp;   // (birth fbits, pixel)
    }
  }
  __syncthreads();
  // per-pixel: compact id + lifetime flush (the ONLY bulk global writes)
  for (int p = tid; p < TPIX; p += LTPB){
    int r = ufind(slbl, p);                // no fires now -> full compression safe
    int gp = ((gr0 + (p>>6))<<8) + gc0 + (p&63);
    CID[gp] = posm[r];
    LIFE[gp] = slife[p];
  }
  __syncthreads();

  // ---- emit surviving internal edges, deduped per root-pair ----
  unsigned* hk = (unsigned*)&el[cur ^ 1][0];   // 2048 u32 slots (free ping-pong half)
  unsigned* hw = slbl;                          // 2048 u32 slots (dead: aux holds roots)
  for (int i = tid; i < LHSZ; i += LTPB){ hk[i] = 0xFFFFFFFFu; hw[i] = 0xFFFFFFFFu; }
  __syncthreads();

  unsigned* ctr = &C[img];
  int Mpad2 = (M + 63) & ~63;
  for (int idx = tid; idx < Mpad2; idx += LTPB){
    bool spill = false;
    u64 rec = 0;
    if (idx < M){
      int e = (int)el[cur][idx];
      unsigned ab = aux[idx];              // round-start roots == final roots (0 fires)
      int a = (int)(ab & 0xFFFFu), b = (int)(ab >> 16);
      int u, v;
      if (e < 2048){ u = e; v = e + 1; } else { u = e - 2048; v = u + 64; }
      unsigned wb = __float_as_uint(fmaxf(sf[u], sf[v]));
      int lo = a < b ? a : b, hi = a < b ? b : a;
      unsigned key = ((unsigned)lo << 11) | (unsigned)hi;   // a,b < 2048 -> 22 bits
      unsigned h = ((key * 2654435761u) >> 21) & (LHSZ-1);
      bool ins = false;
      #pragma unroll
      for (int t = 0; t < 8; ++t){
        unsigned old = atomicCAS(&hk[h], 0xFFFFFFFFu, key);
        if (old == 0xFFFFFFFFu || old == key){ atomicMin(&hw[h], wb); ins = true; break; }
        h = (h + 1) & (LHSZ-1);
      }
      if (!ins){
        spill = true;
        rec = ((u64)wb << 32) | ((u64)posm[a] << 16) | posm[b];
      }
    }
    u64 m = __ballot(spill);
    if (m){
      int pos0 = __popcll(m & ((1ULL<<lane)-1));
      int leader = __ffsll((long long)m)-1;
      unsigned base = 0;
      if (lane == leader) base = atomicAdd(ctr, (unsigned)__popcll(m));
      base = (unsigned)__shfl((int)base, leader);
      if (spill) LA[base + pos0] = rec;
    }
  }
  __syncthreads();
  // flush hash: one record per distinct pair, weight = pair min
  for (int h = tid; h < LHSZ; h += LTPB){
    unsigned key = hk[h];
    bool ok = (key != 0xFFFFFFFFu);
    u64 rec = 0;
    if (ok){
      int a = (int)(key >> 11), b = (int)(key & 0x7FFu);
      rec = ((u64)hw[h] << 32) | ((u64)posm[a] << 16) | posm[b];
    }
    u64 m = __ballot(ok);
    if (m){
      int pos0 = __popcll(m & ((1ULL<<lane)-1));
      int leader = __ffsll((long long)m)-1;
      unsigned base = 0;
      if (lane == leader) base = atomicAdd(ctr, (unsigned)__popcll(m));
      base = (unsigned)__shfl((int)base, leader);
      if (ok) LA[base + pos0] = rec;
    }
  }

  // ---- block top-5 of locally-died bars -> T5g[blk*5..+5) ----
  #pragma unroll
  for (int off = 1; off < 64; off <<= 1){
    float o[5];
    #pragma unroll
    for (int k = 0; k < 5; ++k) o[k] = __shfl_xor(t5[k], off);
    merge5(t5, o);
  }
  if (lane == 0){
    int wv = tid >> 6;
    #pragma unroll
    for (int k = 0; k < 5; ++k) s_t5w[wv*5+k] = t5[k];
  }
  __syncthreads();
  if (tid < 64){
    float u5[5];
    #pragma unroll
    for (int k = 0; k < 5; ++k) u5[k] = (tid < LTPB/64) ? s_t5w[tid*5+k] : -2.0f;
    #pragma unroll
    for (int off = 1; off < 16; off <<= 1){
      float o[5];
      #pragma unroll
      for (int k = 0; k < 5; ++k) o[k] = __shfl_xor(u5[k], off);
      merge5(u5, o);
    }
    if (tid == 0){
      #pragma unroll
      for (int k = 0; k < 5; ++k) T5g[blk*5+k] = u5[k];
    }
  }
}

// fallback rounds (K>KMAX, safety net) — global arrays, fmt16, no dedupe.
// RNK is pre-filled (RNKI from the local kernel).
#define RUN_ROUNDS_GLOBAL(UF, ME, RNK)                                       \
  for (int k = tid; k < K; k += ETPB) UF[k] = (unsigned short)k;             \
  __syncthreads();                                                           \
  for (int rd = 0; rd < 70000 && n > 0; ++rd){                               \
    for (int k = tid; k < K; k += ETPB) ME[k] = 0xFFFFFFFFu;                 \
    if (tid == 0) s_n[0] = 0;                                                \
    __syncthreads();                                                         \
    int Mpad = (n + 63) & ~63;                                               \
    for (int idx = tid; idx < Mpad; idx += ETPB){                            \
      bool keep = false; unsigned wb = 0; int a = 0, b = 0;                  \
      if (idx < n){                                                          \
        u64 rec = src[idx];                                                  \
        wb = (unsigned)(rec >> 32);                                          \
        a = (int)((rec >> 16) & 0xFFFFu);                                    \
        b = (int)(rec & 0xFFFFu);                                            \
        a = ufind16(UF, a); b = ufind16(UF, b);                              \
        if (a != b){ atomicMin(&ME[a], wb); atomicMin(&ME[b], wb); keep = true; } \
      }                                                                      \
      u64 m = __ballot(keep);                                                \
      if (m){                                                                \
        int pos0 = __popcll(m & ((1ULL<<lane)-1));                           \
        int leader = __ffsll((long long)m)-1;                                \
        int base = 0;                                                        \
        if (lane == leader) base = atomicAdd(&s_n[0], __popcll(m));          \
        base = __shfl(base, leader);                                         \
        if (keep) dst[base+pos0] = ((u64)wb<<32)|((u64)(unsigned)a<<16)|(unsigned)b; \
      }                                                                      \
    }                                                                        \
    __syncthreads();                                                         \
    int nn = s_n[0];                                                         \
    for (int idx = tid; idx < nn; idx += ETPB){                              \
      u64 rec = dst[idx];                                                    \
      unsigned wb = (unsigned)(rec >> 32);                                   \
      int a = (int)((rec >> 16) & 0xFFFFu);                                  \
      int b = (int)(rec & 0xFFFFu);                                          \
      bool bd = RNK[b] < RNK[a];                                             \
      int die = bd ? a : b, kp = bd ? b : a;                                 \
      if (ME[die] == wb){                                                    \
        UF[die] = (unsigned short)kp;                                        \
        u64 rk = RNK[die];                                                   \
        life[(unsigned)(rk & 0xFFFFFFFFu)] =                                 \
            __uint_as_float(wb) - __uint_as_float((unsigned)(rk >> 32));     \
      }                                                                      \
    }                                                                        \
    __syncthreads();                                                         \
    u64* t = src; src = dst; dst = t; n = nn;                                \
  }

// ---------------- endgame: 1 block/image, all-LDS UF + ranks + hybrid lists ----------------
__global__ __launch_bounds__(ETPB)
void ph0_endgame(float* __restrict__ LIFEg, unsigned* __restrict__ CIDg,
                 const unsigned* __restrict__ CUTWg, u64* __restrict__ RNKIg,
                 u64* __restrict__ LAg, u64* __restrict__ LBg,
                 const unsigned* __restrict__ C, const unsigned* __restrict__ C2,
                 const float* __restrict__ T5g,
                 float* __restrict__ LOSS, unsigned* __restrict__ DONE,
                 float* __restrict__ out)
{
  const int img = blockIdx.x, tid = threadIdx.x;
  const int lane = tid & 63;
  float* life = LIFEg + img*NPIX;
  unsigned* cid = CIDg + img*NPIX;
  const unsigned* cw = CUTWg + img*NCUT;
  u64* RNKI = RNKIg + (size_t)img*NPIX;
  u64* src = LAg + (size_t)img*NE;
  u64* dst = LBg + (size_t)img*NE;

  // 156.5 KB LDS (<=160 KB/workgroup; 4 blocks -> occupancy moot)
  __shared__ unsigned short s_uf[KMAX];          //  8 KB
  __shared__ unsigned s_meB[2*KMAX];             // 32 KB (double-buffered min/root)
  __shared__ unsigned s_hkB[2*HSZ];              //  8 KB (2 x 1024 hash keys)
  __shared__ unsigned s_hwB[2*HSZ];              //  8 KB (2 x 1024 hash weights)
  __shared__ u64 s_rnk[KMAX];                    // 32 KB ranks
  __shared__ u64 s_lstA[ECAP];                   // 32 KB LDS edge list ping
  __shared__ u64 s_lstB[ECAP];                   // 32 KB LDS edge list pong
  __shared__ unsigned s_fired[KMAX/32];          // 512 B died-bit (t5 dedupe)
  __shared__ float s_w5[(ETPB/64)*5];            // 320 B
  __shared__ int s_n[3];

  const int K = (int)C2[img];
  const int nInt = (int)C[img];

  // build the 2560 cut edges straight into LDS (independent loads: CID x2 + CUTW)
  for (int s = tid; s < NCUT; s += ETPB){
    int gu, gv;
    if (s < 768){ int ci = s >> 8, row = s & 255, col = 63 + (ci<<6); gu = (row<<8)+col; gv = gu+1; }
    else { int k = s - 768; int ri = k >> 8, colh = k & 255, gr = 31 + (ri<<5); gu = (gr<<8)+colh; gv = gu+256; }
    unsigned ia = cid[gu];
    unsigned ib = cid[gv];
    unsigned wb = cw[s];
    s_lstA[s] = ((u64)wb << 32) | ((u64)ia << 16) | ib;
  }
  if (tid < 3) s_n[tid] = 0;
  int n = nInt + NCUT;

  float t5[5] = {-1.f,-1.f,-1.f,-1.f,-1.f};

  if (K <= KMAX){
    // init: uf, ranks (coalesced from RNKI), me[0], hash[0], fired, local top-5s
    for (int k = tid; k < K; k += ETPB){
      s_uf[k] = (unsigned short)k;
      s_rnk[k] = RNKI[k];                  // (birth fbits, pixel): lower = deeper
      s_meB[k] = 0xFFFFFFFFu;
    }
    for (int h = tid; h < HSZ; h += ETPB){ s_hkB[h] = 0xFFFFFFFFu; s_hwB[h] = 0xFFFFFFFFu; }
    if (tid < KMAX/32) s_fired[tid] = 0;
    if (tid < 32*5) ins5(t5, T5g[img*(32*5) + tid]);   // merge local tiles' top-5s
    __syncthreads();

    u64 *lsrc = s_lstA, *ldst = s_lstB;

    for (int rd = 0; rd < 70000; ++rd){
      const int bi = rd & 1;
      unsigned* me = s_meB + bi*KMAX;
      unsigned* hk = s_hkB + bi*HSZ;
      unsigned* hw = s_hwB + bi*HSZ;
      const bool useHash = (n > 1024);
      int Mpad = (n + 63) & ~63;
      // pass A: relabel; hash-dedupe (big rounds) or direct mins; append live
      for (int idx = tid; idx < Mpad; idx += ETPB){
        bool app = false; unsigned wb = 0; int a = 0, b = 0;
        if (idx < n){
          u64 rec;
          if (rd == 0) rec = (idx < NCUT) ? lsrc[idx] : src[idx - NCUT];  // internal recs at src[0..nInt)
          else         rec = (idx < ECAP) ? lsrc[idx] : src[idx];
          a = (int)((rec >> 16) & 0xFFFFu);
          b = (int)(rec & 0xFFFFu);
          a = ufind16(s_uf, a); b = ufind16(s_uf, b);
          if (a != b){
            wb = (unsigned)(rec >> 32);
            if (useHash){
              int lo = a < b ? a : b, hi = a < b ? b : a;
              unsigned key = ((unsigned)lo << 12) | (unsigned)hi;   // ids<4096 -> 24 bits
              unsigned h = ((key * 2654435761u) >> 20) & (HSZ-1);
              bool ins = false;
              #pragma unroll
              for (int t = 0; t < 8; ++t){
                unsigned old = atomicCAS(&hk[h], 0xFFFFFFFFu, key);
                if (old == 0xFFFFFFFFu || old == key){ atomicMin(&hw[h], wb); ins = true; break; }
                h = (h + 1) & (HSZ-1);
              }
              if (!ins){ atomicMin(&me[a], wb); atomicMin(&me[b], wb); app = true; }
            } else {
              atomicMin(&me[a], wb); atomicMin(&me[b], wb); app = true;
            }
          }
        }
        u64 m = __ballot(app);
        if (m){
          int pos0 = __popcll(m & ((1ULL<<lane)-1));
          int leader = __ffsll((long long)m)-1;
          int base = 0;
          if (lane == leader) base = atomicAdd(&s_n[rd%3], __popcll(m));
          base = __shfl(base, leader);
          if (app){
            u64 r = ((u64)wb<<32)|((u64)(unsigned)a<<16)|(unsigned)b;
            int pos = base+pos0;
            if (pos < ECAP) ldst[pos] = r; else dst[pos] = r;
          }
        }
      }
      __syncthreads();                      // B1
      if (useHash){
        // pass B: flush hash — one deduped record per pair
        for (int h = tid; h < HSZ; h += ETPB){
          unsigned key = hk[h];
          bool okk = (key != 0xFFFFFFFFu);
          unsigned wb = 0; int a = 0, b = 0;
          if (okk){
            a = (int)(key >> 12); b = (int)(key & 0xFFFu);
            wb = hw[h];
            atomicMin(&me[a], wb); atomicMin(&me[b], wb);
          }
          u64 m = __ballot(okk);
          if (m){
            int pos0 = __popcll(m & ((1ULL<<lane)-1));
            int leader = __ffsll((long long)m)-1;
            int base = 0;
            if (lane == leader) base = atomicAdd(&s_n[rd%3], __popcll(m));
            base = __shfl(base, leader);
            if (okk){
              u64 r = ((u64)wb<<32)|((u64)(unsigned)a<<16)|(unsigned)b;
              int pos = base+pos0;
              if (pos < ECAP) ldst[pos] = r; else dst[pos] = r;
            }
          }
        }
        __syncthreads();                    // B2 (only on hashed rounds)
      }
      int nn = s_n[rd%3];
      if (nn == 0) break;                   // endgame always progresses; exits via n==0
      // pass C: fire via pass-A roots (frozen in records) — exact elder rule.
      for (int idx = tid; idx < nn; idx += ETPB){
        u64 rec = (idx < ECAP) ? ldst[idx] : dst[idx];
        unsigned wb = (unsigned)(rec >> 32);
        int a = (int)((rec >> 16) & 0xFFFFu);
        int b = (int)(rec & 0xFFFFu);
        u64 ra = s_rnk[a], rb = s_rnk[b];
        bool bd = rb < ra;
        int die = bd ? a : b, kp = bd ? b : a;
        if (me[die] == wb){
          s_uf[die] = (unsigned short)kp;
          unsigned bbit = 1u << (die & 31);
          if (!(atomicOr(&s_fired[die >> 5], bbit) & bbit)){
            u64 rk = bd ? ra : rb;
            ins5(t5, __uint_as_float(wb) - __uint_as_float((unsigned)(rk >> 32)));
          }
        }
      }
      // fire-safe flatten + resets for next round
      for (int k = tid; k < K; k += ETPB) uflat16(s_uf, k);
      {
        unsigned* meN = s_meB + (bi^1)*KMAX;
        for (int k = tid; k < K; k += ETPB) meN[k] = 0xFFFFFFFFu;
        if (nn > 1024){
          unsigned* hkN = s_hkB + (bi^1)*HSZ;
          unsigned* hwN = s_hwB + (bi^1)*HSZ;
          for (int h = tid; h < HSZ; h += ETPB){ hkN[h] = 0xFFFFFFFFu; hwN[h] = 0xFFFFFFFFu; }
        }
        if (tid == 0) s_n[(rd+1)%3] = 0;
      }
      __syncthreads();                      // C
      { u64* t = src; src = dst; dst = t; }
      { u64* t = lsrc; lsrc = ldst; ldst = t; }
      n = nn;
    }
  } else {
    __syncthreads();
    // copy LDS cut edges out so the global fallback sees a contiguous src[0..n)
    for (int s = tid; s < NCUT; s += ETPB) src[nInt + s] = s_lstA[s];
    __syncthreads();
    // scratch: CID region is consumed; first half = uf (u16), second half = me (u32).
    // K <= NPIX/2 = 32768 always (checkerboard bound), so both fit.
    unsigned short* g_uf = (unsigned short*)cid;
    unsigned*       g_me = (unsigned*)(cid + NPIX/2);
    u64*            g_rnk = RNKI;
    RUN_ROUNDS_GLOBAL(g_uf, g_me, g_rnk)
    // fallback path: lifetimes live in life[] (local fires + fallback fires)
    for (int i = tid; i < NPIX; i += ETPB) ins5(t5, life[i]);
  }

  // ---- top-5 via shuffle butterfly -> per-image loss ----
  #pragma unroll
  for (int off = 1; off < 64; off <<= 1){
    float o[5];
    #pragma unroll
    for (int k = 0; k < 5; ++k) o[k] = __shfl_xor(t5[k], off);
    merge5(t5, o);
  }
  if (lane == 0){
    int wv = tid >> 6;
    #pragma unroll
    for (int k = 0; k < 5; ++k) s_w5[wv*5+k] = t5[k];
  }
  __syncthreads();
  if (tid < 64){
    float u5[5];
    #pragma unroll
    for (int k = 0; k < 5; ++k) u5[k] = (tid < ETPB/64) ? s_w5[tid*5+k] : -2.0f;
    #pragma unroll
    for (int off = 1; off < 16; off <<= 1){
      float o[5];
      #pragma unroll
      for (int k = 0; k < 5; ++k) o[k] = __shfl_xor(u5[k], off);
      merge5(u5, o);
    }
    if (tid == 0){
      float lsum = 0.0f;
      #pragma unroll
      for (int k = 0; k < 5; ++k){ float d = u5[k] - 0.5f; lsum += d*d; }  // TARGET_LIFETIME
      atomicExch(&LOSS[img], lsum * 0.2f);   // n_use = 5 always (65535 valid pairs)
      __threadfence();
      unsigned prev = atomicAdd(DONE, 1u);
      if (prev == NIMG - 1){
        float s = 0.0f;
        #pragma unroll
        for (int i = 0; i < NIMG; ++i) s += atomicAdd(&LOSS[i], 0.0f);
        out[0] = s * 25.0f;                  // mean over 4 * LOSS_SCALE(100)
      }
    }
  }
}

extern "C" void kernel_launch(void* const* d_in, const int* in_sizes, int n_in,
                              void* d_out, int out_size, void* d_ws, size_t ws_size,
                              hipStream_t stream)
{
  const float* prob = (const float*)d_in[0];
  const float* roi  = (const float*)d_in[1];
  char* ws = (char*)d_ws;
  const size_t SZL = (size_t)4*NE*8;              // 4,177,920 B per list
  float*    LIFE = (float*)(ws + (1u<<20));
  unsigned* CID  = (unsigned*)(ws + (2u<<20));    // per-pixel compact component id
  unsigned* CUTW = (unsigned*)(ws + (3u<<20));    // cut-edge weights, 4 x 2560 u32
  u64*      LA   = (u64*)(ws + (5u<<20));
  u64*      LB   = (u64*)(ws + (5u<<20) + SZL);
  u64*      RNKI = (u64*)(ws + (5u<<20) + 2*SZL); // per-component rank records
  unsigned* C    = (unsigned*)(ws + (5u<<20) + 2*SZL + (2u<<20));
  unsigned* C2   = C + 4;
  unsigned* DONE = C + 8;
  float*    LOSS = (float*)((char*)C + 64);
  // T5 (128 tiles x 5 floats = 2560 B) carved from LB's tail: endgame global-dst
  // writes use at most n0 << NE-320 entries of each image slice, so the last
  // 320 u64 of the LB region are provably never touched.
  float*    T5   = (float*)(ws + (5u<<20) + 2*SZL - 2560);
  float*    out  = (float*)d_out;

  hipMemsetAsync(C, 0, 64, stream);   // C, C2, DONE (capture-safe memset node)
  ph0_local<<<NBLK_L, LTPB, 0, stream>>>(prob, roi, LIFE, CID, LA, C, C2, CUTW, RNKI, T5);
  ph0_endgame<<<NIMG, ETPB, 0, stream>>>(LIFE, CID, CUTW, RNKI, LA, LB, C, C2, T5, LOSS, DONE, out);
}

// Round 4
// 258.670 us; speedup vs baseline: 1.2175x; 1.0144x over previous
//
#include <hip/hip_runtime.h>
#include <stdint.h>

#define NPIX 65536      // 256*256
#define NRE  65280      // right edges: 256 rows * 255
#define NE   130560     // total edges
#define NIMG 4
#define LTPB 1024                // local kernel threads (R8 showed fewer threads regress)
#define ETPB 1024                // endgame threads
#define NBLK_L (NIMG*32)         // 128 local blocks (32 tiles/image, 32x64 each)
#define TPIX 2048
#define EPAD 4096                // local edge-id space (H:[0,2048) V:[2048,4096))
#define KMAX 4096                // max components/image for LDS endgame (R5: K<=4096 held)
#define HSZ  1024                // endgame LDS dedupe hash slots (per buffer)
#define LHSZ 2048                // local emit dedupe hash slots
#define ECAP 4096                // endgame LDS edge-list slots per buffer (hybrid: spill->global)
#define NCUT 2560                // cut edges per image (3*256 vertical + 7*256 horizontal)
#define MTAILL 256               // local: single-wave tail threshold (list size)
#define ETAIL  256               // endgame: single-wave tail threshold
typedef unsigned long long u64;

// union-find, path compression; ONLY safe while roots are stable (no concurrent fires)
__device__ __forceinline__ int ufind(unsigned* lbl, int x){
  int r = x, c = (int)lbl[r];
  while (c != r){ r = c; c = (int)lbl[r]; }
  while ((int)lbl[x] != r){ int n = (int)lbl[x]; lbl[x] = (unsigned)r; x = n; }
  return r;
}
__device__ __forceinline__ int ufind16(unsigned short* uf, int x){
  int r = x, c = (int)uf[r];
  while (c != r){ r = c; c = (int)uf[r]; }
  while ((int)uf[x] != r){ int n = (int)uf[x]; uf[x] = (unsigned short)r; x = n; }
  return r;
}

// merge two descending-sorted 5-lists (b into a)
__device__ __forceinline__ void merge5(float* a, const float* b){
  float out[5]; int ia = 0, ib = 0;
  #pragma unroll
  for (int k = 0; k < 5; ++k){
    float av = (ia < 5) ? a[ia] : -2.0f;
    float bv = (ib < 5) ? b[ib] : -2.0f;
    if (av >= bv){ out[k] = av; ++ia; } else { out[k] = bv; ++ib; }
  }
  #pragma unroll
  for (int k = 0; k < 5; ++k) a[k] = out[k];
}

// insert v into descending top-5
__device__ __forceinline__ void ins5(float* t5, float v){
  if (v > t5[4]){
    int j = 4;
    while (j > 0 && t5[j-1] < v){ t5[j] = t5[j-1]; --j; }
    t5[j] = v;
  }
}

// ---------------- local (tile) kernel: LDS union-find contraction ----------------
// Outputs per image: LIFE (per-pixel lifetimes of locally-died bars), CID (per-pixel
// compact component id), CUTW (cut-edge weights), RNKI (per-component rank record),
// LA (deduped surviving internal edges, compact ids), T5 (per-tile top-5 lifetimes).
__global__ __launch_bounds__(LTPB)
void ph0_local(const float* __restrict__ prob, const float* __restrict__ roi,
               float* __restrict__ LIFEg, unsigned* __restrict__ CIDg,
               u64* __restrict__ LAg,
               unsigned* __restrict__ C, unsigned* __restrict__ C2,
               unsigned* __restrict__ CUTWg, u64* __restrict__ RNKIg,
               float* __restrict__ T5g)
{
  const int blk = blockIdx.x;
  const int img = blk >> 5;
  const int tile = blk & 31;
  const int tr = tile >> 2, tc = tile & 3;     // 8 rows x 4 cols of tiles
  const int gr0 = tr*32, gc0 = tc*64;
  const int tid = threadIdx.x;
  const int lane = tid & 63;

  const float* pm = prob + img*NPIX;
  const float* rm = roi  + img*NPIX;
  float* LIFE = LIFEg + img*NPIX;
  unsigned* CID = CIDg + img*NPIX;
  unsigned* CUTW = CUTWg + img*NCUT;
  u64* RNKI = RNKIg + (size_t)img*NPIX;
  u64* LA = LAg + (size_t)img*NE;

  __shared__ float          sf[TPIX];      // 8 KB
  __shared__ unsigned       slbl[TPIX];    // 8 KB (later: dedupe hash weights)
  __shared__ unsigned       smeb[2][TPIX]; // 16 KB double-buffered min-weight per root
                                           // (buffer 0 doubles as pos-map after the loop)
  __shared__ float          slife[TPIX];   // 8 KB per-pixel lifetimes (flushed after loop)
  __shared__ unsigned short el[2][EPAD];   // 16 KB ping-pong edge lists (free half: hash keys)
  __shared__ unsigned       aux[EPAD];     // 16 KB round-start roots (a|b<<16)
  __shared__ unsigned       bkw[192];      // cut-edge blocker weights
  __shared__ unsigned short bkp[192];      // blocker pixel (local id)
  __shared__ unsigned       s_fired[TPIX/32]; // 256 B: per-pixel died-bit (t5 dedupe)
  __shared__ float          s_t5w[(LTPB/64)*5]; // 320 B wave top-5s
  __shared__ int s_n[3];                   // rotating round counters

  float t5[5] = {-1.f,-1.f,-1.f,-1.f,-1.f};

  for (int p = tid; p < TPIX; p += LTPB){
    int gp = ((gr0 + (p>>6))<<8) + gc0 + (p&63);
    float fv = 1.0f - pm[gp]*rm[gp];
    sf[p] = fv; slbl[p] = (unsigned)p;
    smeb[0][p] = 0xFFFFFFFFu; smeb[1][p] = 0xFFFFFFFFu;
    slife[p] = 0.0f;
  }
  if (tid < 3) s_n[tid] = 0;
  if (tid < TPIX/32) s_fired[tid] = 0;
  // blocker table: for each tile-boundary pixel, min cut-edge weight
  for (int s = tid; s < 192; s += LTPB){
    unsigned wv = 0xFFFFFFFFu; int p = 0; int gq = -1;
    if (s < 32){ if (tc > 0){ p = s*64;        gq = ((gr0+s)<<8)    + gc0 - 1;  } }
    else if (s < 64){ int k=s-32;  if (tc < 3){ p = k*64+63;  gq = ((gr0+k)<<8)  + gc0 + 64; } }
    else if (s < 128){ int k=s-64; if (tr > 0){ p = k;        gq = ((gr0-1)<<8)  + gc0 + k;  } }
    else { int k=s-128;            if (tr < 7){ p = 31*64+k;  gq = ((gr0+32)<<8) + gc0 + k;  } }
    if (gq >= 0){
      int gp = ((gr0 + (p>>6))<<8) + gc0 + (p&63);
      float fp = 1.0f - pm[gp]*rm[gp];
      float fq = 1.0f - pm[gq]*rm[gq];
      wv = __float_as_uint(fmaxf(fp, fq));
    }
    bkw[s] = wv; bkp[s] = (unsigned short)p;
  }
  __syncthreads();                         // serves as barrier A of round 0

  // export owned cut-edge weights (right cols if tc<3, bottom rows if tr<7).
  if (tid < 192){
    int s = tid;
    if (s >= 32 && s < 64  && tc < 3) CUTW[(tc<<8) | (gr0 + (s-32))] = bkw[s];
    if (s >= 128           && tr < 7) CUTW[768 + (tr<<8) + (gc0 + (s-128))] = bkw[s];
  }

  // ---- local rounds: 2 barriers/round; resets folded into phase 2 (exact
  // coverage: every root read/written next round is an aux endpoint of the
  // survivor list; stale uncovered slots are write-only via blocker atomicMin) ----
  int M = EPAD, cur = 0, rd = 0;
  bool tailm = false;
  for (; rd < 100000; ++rd){
    int nxt = cur ^ 1;
    unsigned* sme  = smeb[rd & 1];
    unsigned* smeN = smeb[(rd+1) & 1];
    int bs = tid - (LTPB - 192);           // blockers on HIGH threads (low ones start phase 1)
    if (bs >= 0){
      unsigned wv = bkw[bs];
      if (wv != 0xFFFFFFFFu) atomicMin(&sme[ufind(slbl, (int)bkp[bs])], wv);
    }
    int Mpad = (M + 63) & ~63;
    // phase 1: relabel, compact survivors, per-root min weight
    for (int idx = tid; idx < Mpad; idx += LTPB){
      bool keep = false; int e=0,u=0,v=0,a=0,b=0;
      if (idx < M){
        e = (rd == 0) ? idx : (int)el[cur][idx];
        bool valid;
        if (e < 2048){ u=e; v=e+1; valid = ((e&63)!=63); }
        else { u=e-2048; v=u+64; valid = ((u>>6)!=31); }
        if (valid){
          a = ufind(slbl,u); b = ufind(slbl,v);
          if (a != b){
            unsigned wb = __float_as_uint(fmaxf(sf[u],sf[v]));
            atomicMin(&sme[a],wb); atomicMin(&sme[b],wb);
            keep = true;
          }
        }
      }
      u64 m = __ballot(keep);
      if (m){
        int pos0 = __popcll(m & ((1ULL<<lane)-1));
        int leader = __ffsll((long long)m)-1;
        int base = 0;
        if (lane == leader) base = atomicAdd(&s_n[rd%3], __popcll(m));
        base = __shfl(base, leader);
        if (keep){
          el[nxt][base+pos0] = (unsigned short)e;
          aux[base+pos0] = (unsigned)a | ((unsigned)b<<16);
        }
      }
    }
    __syncthreads();                       // B: mins + list complete
    int n = s_n[rd%3];
    cur = nxt;
    // n == M  <=>  previous round had zero fires  =>  stable (blocked) state
    if (n == M || n == 0){ M = n; break; }
    M = n;
    // phase 2: fire via round-start roots (frozen in aux) — exact elder rule.
    // Folded: reset next round's sme at the aux endpoints (the exact read set).
    for (int idx = tid; idx < M; idx += LTPB){
      int e = (int)el[cur][idx];
      unsigned ab = aux[idx];
      int a = (int)(ab & 0xFFFFu), b = (int)(ab >> 16);
      int u, v;
      if (e < 2048){ u = e; v = e + 1; } else { u = e - 2048; v = u + 64; }
      float w = fmaxf(sf[u], sf[v]);
      unsigned wb = __float_as_uint(w);
      float fa = sf[a], fb = sf[b];
      bool bd = (fb < fa) || ((fb == fa) && (b < a));   // local order == global order in-tile
      int die = bd ? a : b, keep = bd ? b : a;
      if (sme[die] == wb){
        slbl[die] = (unsigned)keep;
        float lt = w - (bd ? fa : fb);
        slife[die] = lt;                   // idempotent on equal-weight double-fire
        unsigned bbit = 1u << (die & 31);  // t5 insert is NOT idempotent -> dedupe
        if (!(atomicOr(&s_fired[die >> 5], bbit) & bbit)) ins5(t5, lt);
      }
      smeN[a] = 0xFFFFFFFFu; smeN[b] = 0xFFFFFFFFu;
    }
    if (tid == 0) s_n[(rd+1)%3] = 0;
    __syncthreads();                       // bottom (A of round rd+1)
    if (M <= MTAILL){ ++rd; tailm = true; break; }
  }

  // ---- single-wave wave-synchronous tail: zero barriers per round ----
  if (tailm){
    if (tid < 64){
      for (;; ++rd){
        unsigned* sme  = smeb[rd & 1];
        unsigned* smeN = smeb[(rd+1) & 1];
        for (int s = lane; s < 192; s += 64){
          unsigned wv = bkw[s];
          if (wv != 0xFFFFFFFFu) atomicMin(&sme[ufind(slbl, (int)bkp[s])], wv);
        }
        __builtin_amdgcn_wave_barrier();
        int nxt = cur ^ 1;
        int nacc = 0;
        for (int i0 = 0; i0 < M; i0 += 64){
          int idx = i0 + lane;
          bool keep = false; int e = 0, a = 0, b = 0;
          if (idx < M){
            e = (int)el[cur][idx];
            int u, v;
            if (e < 2048){ u = e; v = e + 1; } else { u = e - 2048; v = u + 64; }
            a = ufind(slbl,u); b = ufind(slbl,v);
            if (a != b){
              unsigned wb = __float_as_uint(fmaxf(sf[u],sf[v]));
              atomicMin(&sme[a],wb); atomicMin(&sme[b],wb);
              keep = true;
            }
          }
          u64 mm = __ballot(keep);
          if (keep){
            int pos = nacc + __popcll(mm & ((1ULL<<lane)-1));
            el[nxt][pos] = (unsigned short)e;
            aux[pos] = (unsigned)a | ((unsigned)b<<16);
          }
          nacc += __popcll(mm);
        }
        __builtin_amdgcn_wave_barrier();
        int n = nacc;
        cur = nxt;
        if (n == M || n == 0){ M = n; break; }
        M = n;
        for (int i0 = 0; i0 < M; i0 += 64){
          int idx = i0 + lane;
          if (idx < M){
            int e = (int)el[cur][idx];
            unsigned ab = aux[idx];
            int a = (int)(ab & 0xFFFFu), b = (int)(ab >> 16);
            int u, v;
            if (e < 2048){ u = e; v = e + 1; } else { u = e - 2048; v = u + 64; }
            float w = fmaxf(sf[u], sf[v]);
            unsigned wb = __float_as_uint(w);
            float fa = sf[a], fb = sf[b];
            bool bd = (fb < fa) || ((fb == fa) && (b < a));
            int die = bd ? a : b, kp = bd ? b : a;
            if (sme[die] == wb){
              slbl[die] = (unsigned)kp;
              float lt = w - (bd ? fa : fb);
              slife[die] = lt;
              unsigned bbit = 1u << (die & 31);
              if (!(atomicOr(&s_fired[die >> 5], bbit) & bbit)) ins5(t5, lt);
            }
            smeN[a] = 0xFFFFFFFFu; smeN[b] = 0xFFFFFFFFu;
          }
        }
        __builtin_amdgcn_wave_barrier();
      }
      if (lane == 0){ s_n[0] = M; s_n[1] = cur; }
    }
    __syncthreads();
    M = s_n[0]; cur = s_n[1];
  }

  // ---- compact roots to dense per-image ids, export rank records ----
  unsigned* posm = smeb[0];                // pos map (only root entries written/read)
  for (int p = tid; p < TPIX; p += LTPB){
    if ((int)slbl[p] == p){
      unsigned pos = atomicAdd(&C2[img], 1u);
      posm[p] = pos;
      unsigned gp = (unsigned)(((gr0 + (p>>6))<<8) + gc0 + (p&63));
      RNKI[pos] = ((u64)__float_as_uint(sf[p]) << 32) | gp;   // (birth fbits, pixel)
    }
  }
  __syncthreads();
  // per-pixel: compact id + lifetime flush (the ONLY bulk global writes)
  for (int p = tid; p < TPIX; p += LTPB){
    int r = ufind(slbl, p);                // no fires now -> full compression safe
    int gp = ((gr0 + (p>>6))<<8) + gc0 + (p&63);
    CID[gp] = posm[r];
    LIFE[gp] = slife[p];
  }
  __syncthreads();

  // ---- emit surviving internal edges, deduped per root-pair ----
  unsigned* hk = (unsigned*)&el[cur ^ 1][0];   // 2048 u32 slots (free ping-pong half)
  unsigned* hw = slbl;                          // 2048 u32 slots (dead: aux holds roots)
  for (int i = tid; i < LHSZ; i += LTPB){ hk[i] = 0xFFFFFFFFu; hw[i] = 0xFFFFFFFFu; }
  __syncthreads();

  unsigned* ctr = &C[img];
  int Mpad2 = (M + 63) & ~63;
  for (int idx = tid; idx < Mpad2; idx += LTPB){
    bool spill = false;
    u64 rec = 0;
    if (idx < M){
      int e = (int)el[cur][idx];
      unsigned ab = aux[idx];              // round-start roots == final roots (0 fires)
      int a = (int)(ab & 0xFFFFu), b = (int)(ab >> 16);
      int u, v;
      if (e < 2048){ u = e; v = e + 1; } else { u = e - 2048; v = u + 64; }
      unsigned wb = __float_as_uint(fmaxf(sf[u], sf[v]));
      int lo = a < b ? a : b, hi = a < b ? b : a;
      unsigned key = ((unsigned)lo << 11) | (unsigned)hi;   // a,b < 2048 -> 22 bits
      unsigned h = ((key * 2654435761u) >> 21) & (LHSZ-1);
      bool ins = false;
      #pragma unroll
      for (int t = 0; t < 8; ++t){
        unsigned old = atomicCAS(&hk[h], 0xFFFFFFFFu, key);
        if (old == 0xFFFFFFFFu || old == key){ atomicMin(&hw[h], wb); ins = true; break; }
        h = (h + 1) & (LHSZ-1);
      }
      if (!ins){
        spill = true;
        rec = ((u64)wb << 32) | ((u64)posm[a] << 16) | posm[b];
      }
    }
    u64 m = __ballot(spill);
    if (m){
      int pos0 = __popcll(m & ((1ULL<<lane)-1));
      int leader = __ffsll((long long)m)-1;
      unsigned base = 0;
      if (lane == leader) base = atomicAdd(ctr, (unsigned)__popcll(m));
      base = (unsigned)__shfl((int)base, leader);
      if (spill) LA[base + pos0] = rec;
    }
  }
  __syncthreads();
  // flush hash: one record per distinct pair, weight = pair min
  for (int h = tid; h < LHSZ; h += LTPB){
    unsigned key = hk[h];
    bool ok = (key != 0xFFFFFFFFu);
    u64 rec = 0;
    if (ok){
      int a = (int)(key >> 11), b = (int)(key & 0x7FFu);
      rec = ((u64)hw[h] << 32) | ((u64)posm[a] << 16) | posm[b];
    }
    u64 m = __ballot(ok);
    if (m){
      int pos0 = __popcll(m & ((1ULL<<lane)-1));
      int leader = __ffsll((long long)m)-1;
      unsigned base = 0;
      if (lane == leader) base = atomicAdd(ctr, (unsigned)__popcll(m));
      base = (unsigned)__shfl((int)base, leader);
      if (ok) LA[base + pos0] = rec;
    }
  }

  // ---- block top-5 of locally-died bars -> T5g[blk*5..+5) ----
  #pragma unroll
  for (int off = 1; off < 64; off <<= 1){
    float o[5];
    #pragma unroll
    for (int k = 0; k < 5; ++k) o[k] = __shfl_xor(t5[k], off);
    merge5(t5, o);
  }
  if (lane == 0){
    int wv = tid >> 6;
    #pragma unroll
    for (int k = 0; k < 5; ++k) s_t5w[wv*5+k] = t5[k];
  }
  __syncthreads();
  if (tid < 64){
    float u5[5];
    #pragma unroll
    for (int k = 0; k < 5; ++k) u5[k] = (tid < LTPB/64) ? s_t5w[tid*5+k] : -2.0f;
    #pragma unroll
    for (int off = 1; off < 16; off <<= 1){
      float o[5];
      #pragma unroll
      for (int k = 0; k < 5; ++k) o[k] = __shfl_xor(u5[k], off);
      merge5(u5, o);
    }
    if (tid == 0){
      #pragma unroll
      for (int k = 0; k < 5; ++k) T5g[blk*5+k] = u5[k];
    }
  }
}

// fallback rounds (K>KMAX, safety net) — global arrays, fmt16, no dedupe.
// RNK is pre-filled (RNKI from the local kernel).
#define RUN_ROUNDS_GLOBAL(UF, ME, RNK)                                       \
  for (int k = tid; k < K; k += ETPB) UF[k] = (unsigned short)k;             \
  __syncthreads();                                                           \
  for (int rdg = 0; rdg < 70000 && n > 0; ++rdg){                            \
    for (int k = tid; k < K; k += ETPB) ME[k] = 0xFFFFFFFFu;                 \
    if (tid == 0) s_n[0] = 0;                                                \
    __syncthreads();                                                         \
    int Mpad = (n + 63) & ~63;                                               \
    for (int idx = tid; idx < Mpad; idx += ETPB){                            \
      bool keep = false; unsigned wb = 0; int a = 0, b = 0;                  \
      if (idx < n){                                                          \
        u64 rec = src[idx];                                                  \
        wb = (unsigned)(rec >> 32);                                          \
        a = (int)((rec >> 16) & 0xFFFFu);                                    \
        b = (int)(rec & 0xFFFFu);                                            \
        a = ufind16(UF, a); b = ufind16(UF, b);                              \
        if (a != b){ atomicMin(&ME[a], wb); atomicMin(&ME[b], wb); keep = true; } \
      }                                                                      \
      u64 m = __ballot(keep);                                                \
      if (m){                                                                \
        int pos0 = __popcll(m & ((1ULL<<lane)-1));                           \
        int leader = __ffsll((long long)m)-1;                                \
        int base = 0;                                                        \
        if (lane == leader) base = atomicAdd(&s_n[0], __popcll(m));          \
        base = __shfl(base, leader);                                         \
        if (keep) dst[base+pos0] = ((u64)wb<<32)|((u64)(unsigned)a<<16)|(unsigned)b; \
      }                                                                      \
    }                                                                        \
    __syncthreads();                                                         \
    int nn = s_n[0];                                                         \
    for (int idx = tid; idx < nn; idx += ETPB){                              \
      u64 rec = dst[idx];                                                    \
      unsigned wb = (unsigned)(rec >> 32);                                   \
      int a = (int)((rec >> 16) & 0xFFFFu);                                  \
      int b = (int)(rec & 0xFFFFu);                                          \
      bool bd = RNK[b] < RNK[a];                                             \
      int die = bd ? a : b, kp = bd ? b : a;                                 \
      if (ME[die] == wb){                                                    \
        UF[die] = (unsigned short)kp;                                        \
        u64 rk = RNK[die];                                                   \
        life[(unsigned)(rk & 0xFFFFFFFFu)] =                                 \
            __uint_as_float(wb) - __uint_as_float((unsigned)(rk >> 32));     \
      }                                                                      \
    }                                                                        \
    __syncthreads();                                                         \
    u64* t = src; src = dst; dst = t; n = nn;                                \
  }

// ---------------- endgame: 1 block/image, all-LDS UF + ranks + hybrid lists ----------------
__global__ __launch_bounds__(ETPB)
void ph0_endgame(float* __restrict__ LIFEg, unsigned* __restrict__ CIDg,
                 const unsigned* __restrict__ CUTWg, u64* __restrict__ RNKIg,
                 u64* __restrict__ LAg, u64* __restrict__ LBg,
                 const unsigned* __restrict__ C, const unsigned* __restrict__ C2,
                 const float* __restrict__ T5g,
                 float* __restrict__ LOSS, unsigned* __restrict__ DONE,
                 float* __restrict__ out)
{
  const int img = blockIdx.x, tid = threadIdx.x;
  const int lane = tid & 63;
  float* life = LIFEg + img*NPIX;
  unsigned* cid = CIDg + img*NPIX;
  const unsigned* cw = CUTWg + img*NCUT;
  u64* RNKI = RNKIg + (size_t)img*NPIX;
  u64* src = LAg + (size_t)img*NE;
  u64* dst = LBg + (size_t)img*NE;

  // 156.5 KB LDS (<=160 KB/workgroup; 4 blocks -> occupancy moot)
  __shared__ unsigned short s_uf[KMAX];          //  8 KB
  __shared__ unsigned s_meB[2*KMAX];             // 32 KB (double-buffered min/root)
  __shared__ unsigned s_hkB[2*HSZ];              //  8 KB (2 x 1024 hash keys)
  __shared__ unsigned s_hwB[2*HSZ];              //  8 KB (2 x 1024 hash weights)
  __shared__ u64 s_rnk[KMAX];                    // 32 KB ranks
  __shared__ u64 s_lstA[ECAP];                   // 32 KB LDS edge list ping
  __shared__ u64 s_lstB[ECAP];                   // 32 KB LDS edge list pong
  __shared__ unsigned s_fired[KMAX/32];          // 512 B died-bit (t5 dedupe)
  __shared__ float s_w5[(ETPB/64)*5];            // 320 B
  __shared__ int s_n[3];

  const int K = (int)C2[img];
  const int nInt = (int)C[img];

  // build the 2560 cut edges straight into LDS (independent loads: CID x2 + CUTW)
  for (int s = tid; s < NCUT; s += ETPB){
    int gu, gv;
    if (s < 768){ int ci = s >> 8, row = s & 255, col = 63 + (ci<<6); gu = (row<<8)+col; gv = gu+1; }
    else { int k = s - 768; int ri = k >> 8, colh = k & 255, gr = 31 + (ri<<5); gu = (gr<<8)+colh; gv = gu+256; }
    unsigned ia = cid[gu];
    unsigned ib = cid[gv];
    unsigned wb = cw[s];
    s_lstA[s] = ((u64)wb << 32) | ((u64)ia << 16) | ib;
  }
  if (tid < 3) s_n[tid] = 0;
  int n = nInt + NCUT;

  float t5[5] = {-1.f,-1.f,-1.f,-1.f,-1.f};

  if (K <= KMAX){
    // init: uf, ranks (coalesced from RNKI), me[0] full, hash[0], fired, local top-5s
    for (int k = tid; k < K; k += ETPB){
      s_uf[k] = (unsigned short)k;
      s_rnk[k] = RNKI[k];                  // (birth fbits, pixel): lower = deeper
      s_meB[k] = 0xFFFFFFFFu;
    }
    for (int h = tid; h < HSZ; h += ETPB){ s_hkB[h] = 0xFFFFFFFFu; s_hwB[h] = 0xFFFFFFFFu; }
    if (tid < KMAX/32) s_fired[tid] = 0;
    if (tid < 32*5) ins5(t5, T5g[img*(32*5) + tid]);   // merge local tiles' top-5s
    __syncthreads();

    u64 *lsrc = s_lstA, *ldst = s_lstB;
    int rd = 0; bool tailm = false;

    for (; rd < 70000; ++rd){
      const int bi = rd & 1;
      unsigned* me  = s_meB + bi*KMAX;
      unsigned* meN = s_meB + (bi^1)*KMAX;
      unsigned* hk = s_hkB + bi*HSZ;
      unsigned* hw = s_hwB + bi*HSZ;
      const bool useHash = (n > 1024);
      int Mpad = (n + 63) & ~63;
      // pass A: relabel; hash-dedupe (big rounds) or direct mins; append live
      for (int idx = tid; idx < Mpad; idx += ETPB){
        bool app = false; unsigned wb = 0; int a = 0, b = 0;
        if (idx < n){
          u64 rec;
          if (rd == 0) rec = (idx < NCUT) ? lsrc[idx] : src[idx - NCUT];  // internal recs at src[0..nInt)
          else         rec = (idx < ECAP) ? lsrc[idx] : src[idx];
          a = (int)((rec >> 16) & 0xFFFFu);
          b = (int)(rec & 0xFFFFu);
          a = ufind16(s_uf, a); b = ufind16(s_uf, b);
          if (a != b){
            wb = (unsigned)(rec >> 32);
            if (useHash){
              int lo = a < b ? a : b, hi = a < b ? b : a;
              unsigned key = ((unsigned)lo << 12) | (unsigned)hi;   // ids<4096 -> 24 bits
              unsigned h = ((key * 2654435761u) >> 20) & (HSZ-1);
              bool ins = false;
              #pragma unroll
              for (int t = 0; t < 8; ++t){
                unsigned old = atomicCAS(&hk[h], 0xFFFFFFFFu, key);
                if (old == 0xFFFFFFFFu || old == key){ atomicMin(&hw[h], wb); ins = true; break; }
                h = (h + 1) & (HSZ-1);
              }
              if (!ins){ atomicMin(&me[a], wb); atomicMin(&me[b], wb); app = true; }
            } else {
              atomicMin(&me[a], wb); atomicMin(&me[b], wb); app = true;
            }
          }
        }
        u64 m = __ballot(app);
        if (m){
          int pos0 = __popcll(m & ((1ULL<<lane)-1));
          int leader = __ffsll((long long)m)-1;
          int base = 0;
          if (lane == leader) base = atomicAdd(&s_n[rd%3], __popcll(m));
          base = __shfl(base, leader);
          if (app){
            u64 r = ((u64)wb<<32)|((u64)(unsigned)a<<16)|(unsigned)b;
            int pos = base+pos0;
            if (pos < ECAP) ldst[pos] = r; else dst[pos] = r;
          }
        }
      }
      __syncthreads();                      // B1
      if (useHash){
        // pass B: flush hash — one deduped record per pair
        for (int h = tid; h < HSZ; h += ETPB){
          unsigned key = hk[h];
          bool okk = (key != 0xFFFFFFFFu);
          unsigned wb = 0; int a = 0, b = 0;
          if (okk){
            a = (int)(key >> 12); b = (int)(key & 0xFFFu);
            wb = hw[h];
            atomicMin(&me[a], wb); atomicMin(&me[b], wb);
          }
          u64 m = __ballot(okk);
          if (m){
            int pos0 = __popcll(m & ((1ULL<<lane)-1));
            int leader = __ffsll((long long)m)-1;
            int base = 0;
            if (lane == leader) base = atomicAdd(&s_n[rd%3], __popcll(m));
            base = __shfl(base, leader);
            if (okk){
              u64 r = ((u64)wb<<32)|((u64)(unsigned)a<<16)|(unsigned)b;
              int pos = base+pos0;
              if (pos < ECAP) ldst[pos] = r; else dst[pos] = r;
            }
          }
        }
        __syncthreads();                    // B2 (only on hashed rounds)
      }
      int nn = s_n[rd%3];
      if (nn == 0) break;                   // endgame always progresses; exits via n==0
      // pass C: fire via pass-A roots (frozen in records) — exact elder rule.
      // Folded: reset next round's me at the record endpoints (exact read set).
      for (int idx = tid; idx < nn; idx += ETPB){
        u64 rec = (idx < ECAP) ? ldst[idx] : dst[idx];
        unsigned wb = (unsigned)(rec >> 32);
        int a = (int)((rec >> 16) & 0xFFFFu);
        int b = (int)(rec & 0xFFFFu);
        u64 ra = s_rnk[a], rb = s_rnk[b];
        bool bd = rb < ra;
        int die = bd ? a : b, kp = bd ? b : a;
        if (me[die] == wb){
          s_uf[die] = (unsigned short)kp;
          unsigned bbit = 1u << (die & 31);
          if (!(atomicOr(&s_fired[die >> 5], bbit) & bbit)){
            u64 rk = bd ? ra : rb;
            ins5(t5, __uint_as_float(wb) - __uint_as_float((unsigned)(rk >> 32)));
          }
        }
        meN[a] = 0xFFFFFFFFu; meN[b] = 0xFFFFFFFFu;
      }
      if (nn > 1024){
        unsigned* hkN = s_hkB + (bi^1)*HSZ;
        unsigned* hwN = s_hwB + (bi^1)*HSZ;
        for (int h = tid; h < HSZ; h += ETPB){ hkN[h] = 0xFFFFFFFFu; hwN[h] = 0xFFFFFFFFu; }
      }
      if (tid == 0) s_n[(rd+1)%3] = 0;
      __syncthreads();                      // C
      { u64* t = src; src = dst; dst = t; }
      { u64* t2 = lsrc; lsrc = ldst; ldst = t2; }
      n = nn;
      if (n <= ETAIL){ ++rd; tailm = true; break; }
    }

    // ---- single-wave wave-synchronous tail: zero barriers per round ----
    if (tailm){
      if (tid < 64){
        for (;; ++rd){
          const int bi = rd & 1;
          unsigned* me  = s_meB + bi*KMAX;
          unsigned* meN = s_meB + (bi^1)*KMAX;
          int nacc = 0;
          for (int i0 = 0; i0 < n; i0 += 64){
            int idx = i0 + lane;
            bool app = false; unsigned wb = 0; int a = 0, b = 0;
            if (idx < n){
              u64 rec = lsrc[idx];
              a = (int)((rec >> 16) & 0xFFFFu);
              b = (int)(rec & 0xFFFFu);
              a = ufind16(s_uf, a); b = ufind16(s_uf, b);
              if (a != b){
                wb = (unsigned)(rec >> 32);
                atomicMin(&me[a], wb); atomicMin(&me[b], wb);
                app = true;
              }
            }
            u64 mm = __ballot(app);
            if (app){
              int pos = nacc + __popcll(mm & ((1ULL<<lane)-1));
              ldst[pos] = ((u64)wb<<32)|((u64)(unsigned)a<<16)|(unsigned)b;
            }
            nacc += __popcll(mm);
          }
          __builtin_amdgcn_wave_barrier();
          int nn = nacc;
          if (nn == 0) break;
          for (int i0 = 0; i0 < nn; i0 += 64){
            int idx = i0 + lane;
            if (idx < nn){
              u64 rec = ldst[idx];
              unsigned wb = (unsigned)(rec >> 32);
              int a = (int)((rec >> 16) & 0xFFFFu);
              int b = (int)(rec & 0xFFFFu);
              u64 ra = s_rnk[a], rb = s_rnk[b];
              bool bd = rb < ra;
              int die = bd ? a : b, kp = bd ? b : a;
              if (me[die] == wb){
                s_uf[die] = (unsigned short)kp;
                unsigned bbit = 1u << (die & 31);
                if (!(atomicOr(&s_fired[die >> 5], bbit) & bbit)){
                  u64 rk = bd ? ra : rb;
                  ins5(t5, __uint_as_float(wb) - __uint_as_float((unsigned)(rk >> 32)));
                }
              }
              meN[a] = 0xFFFFFFFFu; meN[b] = 0xFFFFFFFFu;
            }
          }
          __builtin_amdgcn_wave_barrier();
          { u64* t2 = lsrc; lsrc = ldst; ldst = t2; }
          n = nn;
        }
      }
      __syncthreads();
    }
  } else {
    __syncthreads();
    // copy LDS cut edges out so the global fallback sees a contiguous src[0..n)
    for (int s = tid; s < NCUT; s += ETPB) src[nInt + s] = s_lstA[s];
    __syncthreads();
    // scratch: CID region is consumed; first half = uf (u16), second half = me (u32).
    // K <= NPIX/2 = 32768 always (checkerboard bound), so both fit.
    unsigned short* g_uf = (unsigned short*)cid;
    unsigned*       g_me = (unsigned*)(cid + NPIX/2);
    u64*            g_rnk = RNKI;
    RUN_ROUNDS_GLOBAL(g_uf, g_me, g_rnk)
    // fallback path: lifetimes live in life[] (local fires + fallback fires)
    for (int i = tid; i < NPIX; i += ETPB) ins5(t5, life[i]);
  }

  // ---- top-5 via shuffle butterfly -> per-image loss ----
  #pragma unroll
  for (int off = 1; off < 64; off <<= 1){
    float o[5];
    #pragma unroll
    for (int k = 0; k < 5; ++k) o[k] = __shfl_xor(t5[k], off);
    merge5(t5, o);
  }
  if (lane == 0){
    int wv = tid >> 6;
    #pragma unroll
    for (int k = 0; k < 5; ++k) s_w5[wv*5+k] = t5[k];
  }
  __syncthreads();
  if (tid < 64){
    float u5[5];
    #pragma unroll
    for (int k = 0; k < 5; ++k) u5[k] = (tid < ETPB/64) ? s_w5[tid*5+k] : -2.0f;
    #pragma unroll
    for (int off = 1; off < 16; off <<= 1){
      float o[5];
      #pragma unroll
      for (int k = 0; k < 5; ++k) o[k] = __shfl_xor(u5[k], off);
      merge5(u5, o);
    }
    if (tid == 0){
      float lsum = 0.0f;
      #pragma unroll
      for (int k = 0; k < 5; ++k){ float d = u5[k] - 0.5f; lsum += d*d; }  // TARGET_LIFETIME
      atomicExch(&LOSS[img], lsum * 0.2f);   // n_use = 5 always (65535 valid pairs)
      __threadfence();
      unsigned prev = atomicAdd(DONE, 1u);
      if (prev == NIMG - 1){
        float s = 0.0f;
        #pragma unroll
        for (int i = 0; i < NIMG; ++i) s += atomicAdd(&LOSS[i], 0.0f);
        out[0] = s * 25.0f;                  // mean over 4 * LOSS_SCALE(100)
      }
    }
  }
}

extern "C" void kernel_launch(void* const* d_in, const int* in_sizes, int n_in,
                              void* d_out, int out_size, void* d_ws, size_t ws_size,
                              hipStream_t stream)
{
  const float* prob = (const float*)d_in[0];
  const float* roi  = (const float*)d_in[1];
  char* ws = (char*)d_ws;
  const size_t SZL = (size_t)4*NE*8;              // 4,177,920 B per list
  float*    LIFE = (float*)(ws + (1u<<20));
  unsigned* CID  = (unsigned*)(ws + (2u<<20));    // per-pixel compact component id
  unsigned* CUTW = (unsigned*)(ws + (3u<<20));    // cut-edge weights, 4 x 2560 u32
  u64*      LA   = (u64*)(ws + (5u<<20));
  u64*      LB   = (u64*)(ws + (5u<<20) + SZL);
  u64*      RNKI = (u64*)(ws + (5u<<20) + 2*SZL); // per-component rank records
  unsigned* C    = (unsigned*)(ws + (5u<<20) + 2*SZL + (2u<<20));
  unsigned* C2   = C + 4;
  unsigned* DONE = C + 8;
  float*    LOSS = (float*)((char*)C + 64);
  // T5 (128 tiles x 5 floats = 2560 B) carved from LB's tail: endgame global-dst
  // writes use at most n0 << NE-320 entries of each image slice, so the last
  // 320 u64 of the LB region are provably never touched.
  float*    T5   = (float*)(ws + (5u<<20) + 2*SZL - 2560);
  float*    out  = (float*)d_out;

  hipMemsetAsync(C, 0, 64, stream);   // C, C2, DONE (capture-safe memset node)
  ph0_local<<<NBLK_L, LTPB, 0, stream>>>(prob, roi, LIFE, CID, LA, C, C2, CUTW, RNKI, T5);
  ph0_endgame<<<NIMG, ETPB, 0, stream>>>(LIFE, CID, CUTW, RNKI, LA, LB, C, C2, T5, LOSS, DONE, out);
}